// Round 11
// baseline (1116.405 us; speedup 1.0000x reference)
//
#include <hip/hip_runtime.h>
#include <hip/hip_bf16.h>

#define S_  30
#define B_  16
#define Hd  400
#define Vv  18000
#define Ll  512
#define Gg  3
#define Tt  10
#define SBn 480
#define KP  448      // K padded to 14*32
#define NPAD_W 2560
#define NPAD_E 18176
#define NST 141      // vocab N-stripes of 128
#define SG  5
#define EW  18048    // E row stride

typedef unsigned short u16;
typedef __attribute__((ext_vector_type(8))) short bf8;
typedef __attribute__((ext_vector_type(8))) unsigned short u16x8;
typedef __attribute__((ext_vector_type(4))) float f4;

#define INF __builtin_inff()

__device__ __forceinline__ u16 f2bf(float f){
  union { __hip_bfloat16 h; u16 u; } c;
  c.h = __float2bfloat16(f);
  return c.u;
}
__device__ __forceinline__ float bf2f(u16 x){
  union { u16 u; __hip_bfloat16 h; } c;
  c.u = x;
  return __bfloat162float(c.h);
}

// ---------------- setup kernels ----------------

__global__ void k_setup_w(const float* __restrict__ Wih, const float* __restrict__ Whh,
                          u16* __restrict__ whi, u16* __restrict__ wlo){
  long total = (long)NPAD_W * KP;
  for (long idx = (long)blockIdx.x*256 + threadIdx.x; idx < total; idx += (long)gridDim.x*256){
    int r = (int)(idx / KP), k = (int)(idx - (long)r*KP);
    float v = 0.f;
    if (k < Hd){
      if (r < 1200) v = Wih[(long)r*Hd + k];
      else if (r >= 1280 && r < 2480) v = Whh[(long)(r-1280)*Hd + k];
    }
    u16 hi = f2bf(v);
    whi[idx] = hi;
    wlo[idx] = f2bf(v - bf2f(hi));
  }
}

__global__ void k_setup_e(const float* __restrict__ emb, u16* __restrict__ ebf){
  long total = (long)NPAD_E * KP;
  for (long idx = (long)blockIdx.x*256 + threadIdx.x; idx < total; idx += (long)gridDim.x*256){
    long r = idx / KP; int k = (int)(idx - r*KP);
    float v = (r < Vv && k < Hd) ? emb[r*Hd + k] : 0.f;
    ebf[idx] = f2bf(v);
  }
}

__global__ void k_setup_xh(const float* __restrict__ ehid, const float* __restrict__ semb,
                           const int* __restrict__ didx, const int* __restrict__ sidx,
                           float* __restrict__ X, float* __restrict__ Hh,
                           u16* __restrict__ Xhi, u16* __restrict__ Xlo,
                           u16* __restrict__ Hhi, u16* __restrict__ Hlo){
  int m = blockIdx.x, k = threadIdx.x;   // 512 blocks x 448 threads
  float xv = 0.f, hv = 0.f;
  if (m < SBn && k < Hd){
    int s = m >> 4, b = m & 15;
    xv = semb[(long)didx[s]*Hd + k] + semb[(long)sidx[s]*Hd + k];
    hv = ehid[(long)b*Hd + k];
  }
  long o = (long)m*KP + k;
  X[o] = xv;  Hh[o] = hv;
  u16 xh = f2bf(xv); Xhi[o] = xh; Xlo[o] = f2bf(xv - bf2f(xh));
  u16 hh = f2bf(hv); Hhi[o] = hh; Hlo[o] = f2bf(hv - bf2f(hh));
}

// transpose Eo[b][l][k] -> EoT[b][k][l]
__global__ __launch_bounds__(256) void k_setup_t(const float* __restrict__ Eo, float* __restrict__ EoT){
  __shared__ float tile[64][65];
  int b = blockIdx.y;
  int kt = blockIdx.x / 8, lt = blockIdx.x - kt*8;
  int k0 = kt*64, l0 = lt*64;
  int c = threadIdx.x & 63, rb = threadIdx.x >> 6;
  #pragma unroll
  for (int p = 0; p < 16; ++p){
    int r = p*4 + rb;
    tile[r][c] = (k0 + c < Hd) ? Eo[((long)b*Ll + l0 + r)*Hd + k0 + c] : 0.f;
  }
  __syncthreads();
  #pragma unroll
  for (int p = 0; p < 16; ++p){
    int r = p*4 + rb;
    if (k0 + r < Hd) EoT[((long)b*Hd + k0 + r)*Ll + l0 + c] = tile[c][r];
  }
}

// ---------------- GRU GEMM (split bf16, 3 MFMAs) — R6 structure, pre-converted A ----------------
// grid (15, 20): x = m-tile(32); y: 0..9 seg0 (A=X, W_ih), 10..19 seg1 (A=Hh, W_hh). BN=128.
__global__ __launch_bounds__(256) void k_ggemm(
    const u16* __restrict__ Xhi, const u16* __restrict__ Xlo,
    const u16* __restrict__ Hhi, const u16* __restrict__ Hlo,
    const u16* __restrict__ Bhi, const u16* __restrict__ Blo,
    float* __restrict__ Gm)
{
  __shared__ u16 As_hi[32*40], As_lo[32*40];
  __shared__ u16 Bs_hi[128*40], Bs_lo[128*40];
  int tid = threadIdx.x;
  int mt = blockIdx.x, yt = blockIdx.y;
  int seg = yt >= 10 ? 1 : 0, nt = seg ? yt-10 : yt;
  const u16* Ahi = seg ? Hhi : Xhi;
  const u16* Alo = seg ? Hlo : Xlo;
  int m0 = mt*32;
  long brow0 = (long)seg*1280 + (long)nt*128;
  int w = tid>>6, l = tid&63, lr = l&15, kg = l>>4;
  f4 acc[2][2] = {};
  int arow = tid>>3, ac4 = (tid&7)*4;
  int br4 = tid>>2, bc8 = (tid&3)*8;
  const u16* aPh = Ahi + (long)(m0+arow)*KP + ac4;
  const u16* aPl = Alo + (long)(m0+arow)*KP + ac4;
  for (int ks = 0; ks < 14; ++ks){
    int k0 = ks*32;
    __syncthreads();
    *(ushort4*)&As_hi[arow*40+ac4] = *(const ushort4*)(aPh + k0);
    *(ushort4*)&As_lo[arow*40+ac4] = *(const ushort4*)(aPl + k0);
    #pragma unroll
    for (int p = 0; p < 2; ++p){
      long row = brow0 + p*64 + br4;
      *(uint4*)&Bs_hi[(p*64+br4)*40+bc8] = *(const uint4*)(Bhi + row*KP + k0 + bc8);
      *(uint4*)&Bs_lo[(p*64+br4)*40+bc8] = *(const uint4*)(Blo + row*KP + k0 + bc8);
    }
    __syncthreads();
    bf8 ah[2], al[2], bh[2], bl[2];
    #pragma unroll
    for (int i = 0; i < 2; ++i){
      ah[i] = *(const bf8*)&As_hi[(i*16+lr)*40 + kg*8];
      al[i] = *(const bf8*)&As_lo[(i*16+lr)*40 + kg*8];
    }
    #pragma unroll
    for (int j = 0; j < 2; ++j){
      int r = w*32 + j*16 + lr;
      bh[j] = *(const bf8*)&Bs_hi[r*40 + kg*8];
      bl[j] = *(const bf8*)&Bs_lo[r*40 + kg*8];
    }
    #pragma unroll
    for (int i = 0; i < 2; ++i)
      #pragma unroll
      for (int j = 0; j < 2; ++j){
        acc[i][j] = __builtin_amdgcn_mfma_f32_16x16x32_bf16(ah[i], bh[j], acc[i][j], 0,0,0);
        acc[i][j] = __builtin_amdgcn_mfma_f32_16x16x32_bf16(ah[i], bl[j], acc[i][j], 0,0,0);
        acc[i][j] = __builtin_amdgcn_mfma_f32_16x16x32_bf16(al[i], bh[j], acc[i][j], 0,0,0);
      }
  }
  #pragma unroll
  for (int i = 0; i < 2; ++i)
    #pragma unroll
    for (int j = 0; j < 2; ++j){
      int nl = nt*128 + w*32 + j*16 + lr;
      if (nl < 1200){
        int col = seg*1200 + nl;
        int mrow = m0 + i*16 + kg*4;
        #pragma unroll
        for (int r = 0; r < 4; ++r)
          Gm[(long)(mrow+r)*2400 + col] = acc[i][j][r];
      }
    }
}

// ---------------- fused GRU-combine + attention + p_gen (+gates), shuffle reductions ----------
__global__ __launch_bounds__(512) void k_attn(
    const float* __restrict__ Eo, const float* __restrict__ EoT, const int* __restrict__ cmask,
    const float* __restrict__ Gm, const float* __restrict__ bih, const float* __restrict__ bhh,
    float* __restrict__ Hh, u16* __restrict__ Hhi, u16* __restrict__ Hlo,
    const float* __restrict__ X,
    const float* __restrict__ wr, const float* __restrict__ wrb,
    const float* __restrict__ wg, const float* __restrict__ wgb,
    float* __restrict__ cp, float* __restrict__ pgen, float* __restrict__ og, int t)
{
  __shared__ float sh_h[SG][Hd];
  __shared__ float sh_c[SG][Hd];
  __shared__ float sh_p[SG][Ll];
  __shared__ float buf[4*SG*Ll];
  __shared__ float wred[2][SG*8];
  int tid = threadIdx.x, b = blockIdx.y, s0 = blockIdx.x*SG;
  int lane = tid & 63, wid = tid >> 6;

  // GRU combine for our 5 rows
  for (int idx = tid; idx < SG*Hd; idx += 512){
    int sg = idx / Hd, j = idx - sg*Hd;
    long m = (long)(s0+sg)*B_ + b;
    const float* g = Gm + m*2400;
    float r = 1.f/(1.f+expf(-(g[j]     + bih[j]     + g[1200+j] + bhh[j])));
    float z = 1.f/(1.f+expf(-(g[400+j] + bih[400+j] + g[1600+j] + bhh[400+j])));
    float n = tanhf(g[800+j] + bih[800+j] + r*(g[2000+j] + bhh[800+j]));
    float h = (1.f-z)*n + z*Hh[m*KP + j];
    sh_h[sg][j] = h;
    Hh[m*KP + j] = h;
    u16 hh = f2bf(h);
    Hhi[m*KP + j] = hh;
    Hlo[m*KP + j] = f2bf(h - bf2f(hh));
  }
  __syncthreads();

  // scores: thread = (lq=tid&127 -> l0=4*lq, kq=tid>>7), coalesced f4 reads of EoT
  {
    int lq = tid & 127, kq = tid >> 7;
    int l0 = lq*4;
    const float* ebase = EoT + (long)b*Hd*Ll;
    f4 sc[SG];
    #pragma unroll
    for (int sg = 0; sg < SG; ++sg) sc[sg] = f4{0.f,0.f,0.f,0.f};
    int k0 = kq*100;
    for (int k = k0; k < k0+100; k += 4){
      f4 h4[SG];
      #pragma unroll
      for (int sg = 0; sg < SG; ++sg) h4[sg] = *(const f4*)&sh_h[sg][k];
      #pragma unroll
      for (int kk = 0; kk < 4; ++kk){
        f4 e = *(const f4*)&ebase[(long)(k+kk)*Ll + l0];
        #pragma unroll
        for (int sg = 0; sg < SG; ++sg){
          float hk = h4[sg][kk];
          sc[sg].x += e.x*hk; sc[sg].y += e.y*hk; sc[sg].z += e.z*hk; sc[sg].w += e.w*hk;
        }
      }
    }
    #pragma unroll
    for (int sg = 0; sg < SG; ++sg)
      *(f4*)&buf[(kq*SG+sg)*Ll + l0] = sc[sg];
  }
  __syncthreads();

  // combine partials, mask; softmax via wave shuffle + 8-entry cross-wave combine
  float v[SG];
  {
    bool mok = cmask[b*Ll + tid] != 0;
    #pragma unroll
    for (int sg = 0; sg < SG; ++sg){
      float x = buf[sg*Ll+tid] + buf[(SG+sg)*Ll+tid] + buf[(2*SG+sg)*Ll+tid] + buf[(3*SG+sg)*Ll+tid];
      v[sg] = mok ? x : -INF;
    }
  }
  #pragma unroll
  for (int sg = 0; sg < SG; ++sg){
    float m_ = v[sg];
    #pragma unroll
    for (int d = 1; d < 64; d <<= 1) m_ = fmaxf(m_, __shfl_xor(m_, d));
    if (lane == 0) wred[0][sg*8 + wid] = m_;
  }
  __syncthreads();
  float p[SG];
  #pragma unroll
  for (int sg = 0; sg < SG; ++sg){
    float mx = wred[0][sg*8];
    #pragma unroll
    for (int q = 1; q < 8; ++q) mx = fmaxf(mx, wred[0][sg*8+q]);
    p[sg] = expf(v[sg] - mx);
    float s_ = p[sg];
    #pragma unroll
    for (int d = 1; d < 64; d <<= 1) s_ += __shfl_xor(s_, d);
    if (lane == 0) wred[1][sg*8 + wid] = s_;
  }
  __syncthreads();
  #pragma unroll
  for (int sg = 0; sg < SG; ++sg){
    float sum = 0.f;
    #pragma unroll
    for (int q = 0; q < 8; ++q) sum += wred[1][sg*8+q];
    float pp = p[sg] / sum;
    sh_p[sg][tid] = pp;
    cp[((long)(s0+sg)*B_ + b)*Ll + tid] = pp;
  }
  __syncthreads();

  // ctx: thread = (k4 = tid&127 [<100 active], lq = tid>>7)
  {
    int k4 = tid & 127, lq = tid >> 7;
    if (k4 < 100){
      int k = k4*4;
      f4 cacc[SG];
      #pragma unroll
      for (int sg = 0; sg < SG; ++sg) cacc[sg] = f4{0.f,0.f,0.f,0.f};
      for (int li = 0; li < 128; li += 4){
        int l2 = lq*128 + li;
        f4 pv[SG];
        #pragma unroll
        for (int sg = 0; sg < SG; ++sg) pv[sg] = *(const f4*)&sh_p[sg][l2];
        #pragma unroll
        for (int jj = 0; jj < 4; ++jj){
          f4 e = *(const f4*)&Eo[((long)b*Ll + l2 + jj)*Hd + k];
          #pragma unroll
          for (int sg = 0; sg < SG; ++sg){
            float pw = pv[sg][jj];
            cacc[sg].x += e.x*pw; cacc[sg].y += e.y*pw; cacc[sg].z += e.z*pw; cacc[sg].w += e.w*pw;
          }
        }
      }
      #pragma unroll
      for (int sg = 0; sg < SG; ++sg)
        *(f4*)&buf[(lq*SG+sg)*Hd + k] = cacc[sg];
    }
  }
  __syncthreads();
  if (tid < Hd){
    #pragma unroll
    for (int sg = 0; sg < SG; ++sg)
      sh_c[sg][tid] = buf[sg*Hd+tid] + buf[(SG+sg)*Hd+tid] + buf[(2*SG+sg)*Hd+tid] + buf[(3*SG+sg)*Hd+tid];
  }
  __syncthreads();

  // p_gen = sigmoid([h,c,x].wr + b)  (shuffle + 8-entry combine)
  {
    float part[SG] = {0,0,0,0,0};
    for (int j = tid; j < 1200; j += 512){
      float wv = wr[j];
      #pragma unroll
      for (int sg = 0; sg < SG; ++sg){
        float xv;
        if (j < 400) xv = sh_h[sg][j];
        else if (j < 800) xv = sh_c[sg][j-400];
        else xv = X[((long)(s0+sg)*B_ + b)*KP + (j-800)];
        part[sg] += xv*wv;
      }
    }
    #pragma unroll
    for (int sg = 0; sg < SG; ++sg){
      float s_ = part[sg];
      #pragma unroll
      for (int d = 1; d < 64; d <<= 1) s_ += __shfl_xor(s_, d);
      if (lane == 0) wred[0][sg*8 + wid] = s_;
    }
    __syncthreads();
    if (tid < SG){
      float sum = 0.f;
      #pragma unroll
      for (int q = 0; q < 8; ++q) sum += wred[0][tid*8+q];
      pgen[(long)(s0+tid)*B_ + b] = 1.f/(1.f+expf(-(sum + wrb[0])));
    }
  }

  // gates logits at t==0
  if (t == 0){
    for (int g = 0; g < Gg; ++g){
      float pt[SG] = {0,0,0,0,0};
      if (tid < Hd){
        float wv = wg[g*Hd + tid];
        #pragma unroll
        for (int sg = 0; sg < SG; ++sg) pt[sg] = sh_c[sg][tid]*wv;
      }
      __syncthreads();   // protect wred[1] reuse across g iterations
      #pragma unroll
      for (int sg = 0; sg < SG; ++sg){
        float s_ = pt[sg];
        #pragma unroll
        for (int d = 1; d < 64; d <<= 1) s_ += __shfl_xor(s_, d);
        if (lane == 0) wred[1][sg*8 + wid] = s_;
      }
      __syncthreads();
      if (tid < SG){
        float sum = 0.f;
        #pragma unroll
        for (int q = 0; q < 8; ++q) sum += wred[1][tid*8+q];
        og[((long)b*S_ + (s0+tid))*Gg + g] = sum + wgb[g];
      }
    }
  }
}

// ---------------- vocab GEMM — R6 structure, BK=64 (half the barriers) ----------
// grid (141, 4): x = n-stripe (128 cols), y = m-tile: m0 in {0,128,256,352}
__global__ __launch_bounds__(256) void k_vgemm(
    const u16* __restrict__ Abf, const u16* __restrict__ Bhi,
    u16* __restrict__ E, float* __restrict__ pmax, float* __restrict__ psum)
{
  __shared__ u16 As[128*72], Bs[128*72];
  __shared__ float redm[2][128], reds[2][128];
  int tid = threadIdx.x;
  int ns = blockIdx.x, mt = blockIdx.y;
  int m0 = (mt == 3) ? 352 : mt*128;   // rows 352-383 duplicated by mt=2: bitwise-identical writes
  long brow0 = (long)ns*128;
  int w = tid>>6, l = tid&63, lr = l&15, kg = l>>4;
  int wm = w>>1, wn = w&1;
  int srow = tid>>1, sc = (tid&1)*32;          // 2 threads/row, 32 u16 each
  const u16* aP = Abf + (long)(m0+srow)*KP + sc;
  const u16* bP = Bhi + (brow0+srow)*KP + sc;
  int so = srow*72 + sc;
  f4 acc[4][4] = {};
  for (int ks = 0; ks < 7; ++ks){
    int k0 = ks*64;
    __syncthreads();
    #pragma unroll
    for (int q = 0; q < 4; ++q){
      *(uint4*)&As[so + q*8] = *(const uint4*)(aP + k0 + q*8);
      *(uint4*)&Bs[so + q*8] = *(const uint4*)(bP + k0 + q*8);
    }
    __syncthreads();
    #pragma unroll
    for (int sub = 0; sub < 2; ++sub){
      int kc = sub*32 + kg*8;
      bf8 a[4], b[4];
      #pragma unroll
      for (int i = 0; i < 4; ++i) a[i] = *(const bf8*)&As[(wm*64 + i*16 + lr)*72 + kc];
      #pragma unroll
      for (int j = 0; j < 4; ++j) b[j] = *(const bf8*)&Bs[(wn*64 + j*16 + lr)*72 + kc];
      #pragma unroll
      for (int i = 0; i < 4; ++i)
        #pragma unroll
        for (int j = 0; j < 4; ++j)
          acc[i][j] = __builtin_amdgcn_mfma_f32_16x16x32_bf16(a[i], b[j], acc[i][j], 0,0,0);
    }
  }
  // epilogue: per-row stripe max
  #pragma unroll
  for (int i = 0; i < 4; ++i)
    #pragma unroll
    for (int r = 0; r < 4; ++r){
      float mxv = -INF;
      #pragma unroll
      for (int j = 0; j < 4; ++j){
        int col = (int)brow0 + wn*64 + j*16 + lr;
        if (col < Vv) mxv = fmaxf(mxv, acc[i][j][r]);
      }
      #pragma unroll
      for (int d = 1; d < 16; d <<= 1) mxv = fmaxf(mxv, __shfl_xor(mxv, d));
      if (lr == 0) redm[wn][wm*64 + i*16 + kg*4 + r] = mxv;
    }
  __syncthreads();
  // exp, store bf16 E, per-row sums
  #pragma unroll
  for (int i = 0; i < 4; ++i)
    #pragma unroll
    for (int r = 0; r < 4; ++r){
      int rl = wm*64 + i*16 + kg*4 + r;
      float cmx = fmaxf(redm[0][rl], redm[1][rl]);
      float ssum = 0.f;
      long erow = (long)(m0 + rl)*EW;
      #pragma unroll
      for (int j = 0; j < 4; ++j){
        int col = (int)brow0 + wn*64 + j*16 + lr;
        float e = (col < Vv) ? expf(acc[i][j][r] - cmx) : 0.f;
        E[erow + col] = f2bf(e);
        ssum += e;
      }
      #pragma unroll
      for (int d = 1; d < 16; d <<= 1) ssum += __shfl_xor(ssum, d);
      if (lr == 0) reds[wn][rl] = ssum;
    }
  __syncthreads();
  if (tid < 128){
    pmax[(long)(m0+tid)*NST + ns] = fmaxf(redm[0][tid], redm[1][tid]);
    psum[(long)(m0+tid)*NST + ns] = reds[0][tid] + reds[1][tid];
  }
}

// ---------------- fused: LSE-combine + finalize + scatter + argmax + greedy feedback ----------
__global__ __launch_bounds__(512) void k_final(
    const u16* __restrict__ E, const float* __restrict__ pmax, const float* __restrict__ psum,
    const float* __restrict__ pgen, const float* __restrict__ cp,
    const int* __restrict__ cidx, const int* __restrict__ cmask,
    const float* __restrict__ emb, float* __restrict__ out,
    float* __restrict__ X, u16* __restrict__ Xhi, u16* __restrict__ Xlo, int t)
{
  __shared__ float scat[Vv];
  __shared__ float scale[NST];
  __shared__ float am[256], asum[256];
  __shared__ float rv[512];
  __shared__ int   ri[512];
  int tid = threadIdx.x, m = blockIdx.x;
  int b = m & 15, s = m >> 4;
  if (tid < 256){
    am[tid]   = tid < NST ? pmax[(long)m*NST + tid] : -1e30f;
    asum[tid] = tid < NST ? psum[(long)m*NST + tid] : 0.f;
  }
  for (int i = tid; i < Vv; i += 512) scat[i] = 0.f;
  __syncthreads();
  for (int o = 128; o > 0; o >>= 1){
    if (tid < o){
      float m2 = am[tid+o], M = fmaxf(am[tid], m2);
      asum[tid] = asum[tid]*expf(am[tid]-M) + asum[tid+o]*expf(m2-M);
      am[tid] = M;
    }
    __syncthreads();
  }
  float gmx = am[0], pg = pgen[m];
  float sc0 = pg / asum[0];
  if (tid < NST) scale[tid] = sc0 * expf(pmax[(long)m*NST + tid] - gmx);
  if (cmask[b*Ll + tid]){
    float vv = (1.f - pg)*cp[(long)m*Ll + tid];
    atomicAdd(&scat[cidx[b*Ll + tid]], vv);
  }
  __syncthreads();
  long eb = (long)m*EW;
  long ob = ((long)(b*S_ + s)*Tt + t)*(long)Vv;
  float bv = -1.f; int bi = 0;
  for (int i = tid; i < Vv/8; i += 512){
    u16x8 ev = *(const u16x8*)&E[eb + i*8];
    float sc = scale[(i*8) >> 7];
    f4 s0 = *(const f4*)&scat[i*8];
    f4 s1 = *(const f4*)&scat[i*8 + 4];
    f4 o0, o1;
    o0.x = sc*bf2f(ev[0]) + s0.x; o0.y = sc*bf2f(ev[1]) + s0.y;
    o0.z = sc*bf2f(ev[2]) + s0.z; o0.w = sc*bf2f(ev[3]) + s0.w;
    o1.x = sc*bf2f(ev[4]) + s1.x; o1.y = sc*bf2f(ev[5]) + s1.y;
    o1.z = sc*bf2f(ev[6]) + s1.z; o1.w = sc*bf2f(ev[7]) + s1.w;
    *(f4*)&out[ob + i*8]     = o0;
    *(f4*)&out[ob + i*8 + 4] = o1;
    int n0 = i*8;
    if (o0.x > bv){ bv = o0.x; bi = n0;   }
    if (o0.y > bv){ bv = o0.y; bi = n0+1; }
    if (o0.z > bv){ bv = o0.z; bi = n0+2; }
    if (o0.w > bv){ bv = o0.w; bi = n0+3; }
    if (o1.x > bv){ bv = o1.x; bi = n0+4; }
    if (o1.y > bv){ bv = o1.y; bi = n0+5; }
    if (o1.z > bv){ bv = o1.z; bi = n0+6; }
    if (o1.w > bv){ bv = o1.w; bi = n0+7; }
  }
  rv[tid] = bv; ri[tid] = bi;
  __syncthreads();
  for (int o = 256; o > 0; o >>= 1){
    if (tid < o){
      float v2 = rv[tid+o]; int i2 = ri[tid+o];
      if (v2 > rv[tid] || (v2 == rv[tid] && i2 < ri[tid])){ rv[tid] = v2; ri[tid] = i2; }
    }
    __syncthreads();
  }
  int win = ri[0];
  if (tid < Hd){
    float v = emb[(long)win*Hd + tid];
    long o = (long)m*KP + tid;
    X[o] = v;
    u16 hi = f2bf(v);
    Xhi[o] = hi;
    Xlo[o] = f2bf(v - bf2f(hi));
  }
}

// ---------------- launcher ----------------
extern "C" void kernel_launch(void* const* d_in, const int* in_sizes, int n_in,
                              void* d_out, int out_size, void* d_ws, size_t ws_size,
                              hipStream_t stream)
{
  const float* ehid  = (const float*)d_in[0];
  const float* eout  = (const float*)d_in[1];
  const int*   cidx  = (const int*)d_in[2];
  const int*   cmask = (const int*)d_in[3];
  const float* emb   = (const float*)d_in[5];
  const float* semb  = (const float*)d_in[6];
  const int*   didx  = (const int*)d_in[7];
  const int*   sidx  = (const int*)d_in[8];
  const float* Wih   = (const float*)d_in[9];
  const float* Whh   = (const float*)d_in[10];
  const float* bih   = (const float*)d_in[11];
  const float* bhh   = (const float*)d_in[12];
  const float* wr    = (const float*)d_in[13];
  const float* wrb   = (const float*)d_in[14];
  const float* wg    = (const float*)d_in[15];
  const float* wgb   = (const float*)d_in[16];
  float* out = (float*)d_out;

  char* ws = (char*)d_ws;
  u16*   ws_hi = (u16*)(ws + 0);            //  2,293,760
  u16*   ws_lo = (u16*)(ws + 2293760);      //  2,293,760
  u16*   ebf   = (u16*)(ws + 4587520);      // 16,285,696
  float* EoT   = (float*)(ws + 20873216);   // 13,107,200
  float* X     = (float*)(ws + 33980416);   //    917,504
  u16*   Xhi   = (u16*)(ws + 34897920);     //    458,752
  u16*   Xlo   = (u16*)(ws + 35356672);     //    458,752
  float* Hh    = (float*)(ws + 35815424);   //    917,504
  u16*   Hhi   = (u16*)(ws + 36732928);     //    458,752
  u16*   Hlo   = (u16*)(ws + 37191680);     //    458,752
  float* Gm    = (float*)(ws + 37650432);   //  4,608,000
  u16*   E     = (u16*)(ws + 42258432);     // 18,481,152 (512 x 18048 bf16)
  float* cp    = (float*)(ws + 60739584);   //    983,040
  float* pg    = (float*)(ws + 61722624);   //      2,048
  float* pmax  = (float*)(ws + 61724672);   //    288,768
  float* psum  = (float*)(ws + 62013440);   //    288,768
  float* og = out + (long)B_*S_*Tt*Vv;

  k_setup_w <<<4480, 256, 0, stream>>>(Wih, Whh, ws_hi, ws_lo);
  k_setup_e <<<4096, 256, 0, stream>>>(emb, ebf);
  k_setup_xh<<<512, 448, 0, stream>>>(ehid, semb, didx, sidx, X, Hh, Xhi, Xlo, Hhi, Hlo);
  k_setup_t <<<dim3(56,16), 256, 0, stream>>>(eout, EoT);

  for (int t = 0; t < Tt; ++t){
    k_ggemm <<<dim3(15,20), 256, 0, stream>>>(Xhi, Xlo, Hhi, Hlo, ws_hi, ws_lo, Gm);
    k_attn  <<<dim3(6,16), 512, 0, stream>>>(eout, EoT, cmask, Gm, bih, bhh, Hh, Hhi, Hlo, X,
                                             wr, wrb, wg, wgb, cp, pg, og, t);
    k_vgemm <<<dim3(141,4), 256, 0, stream>>>(Hhi, ebf, E, pmax, psum);
    k_final <<<480, 512, 0, stream>>>(E, pmax, psum, pg, cp, cidx, cmask, emb, out, X, Xhi, Xlo, t);
  }
}

// Round 12
// 1003.735 us; speedup vs baseline: 1.1123x; 1.1123x over previous
//
#include <hip/hip_runtime.h>
#include <hip/hip_bf16.h>

#define S_  30
#define B_  16
#define Hd  400
#define Vv  18000
#define Ll  512
#define Gg  3
#define Tt  10
#define SBn 480
#define KP  448      // K padded to 14*32
#define NPAD_W 2560
#define NPAD_E 18176
#define NST 141      // vocab N-stripes of 128
#define SG  2        // slots per k_attn block (R12: 5 -> 2 for occupancy)
#define EW  18048    // E row stride

typedef unsigned short u16;
typedef __attribute__((ext_vector_type(8))) short bf8;
typedef __attribute__((ext_vector_type(8))) unsigned short u16x8;
typedef __attribute__((ext_vector_type(4))) float f4;

#define INF __builtin_inff()

__device__ __forceinline__ u16 f2bf(float f){
  union { __hip_bfloat16 h; u16 u; } c;
  c.h = __float2bfloat16(f);
  return c.u;
}
__device__ __forceinline__ float bf2f(u16 x){
  union { u16 u; __hip_bfloat16 h; } c;
  c.u = x;
  return __bfloat162float(c.h);
}

// ---------------- setup kernels ----------------

__global__ void k_setup_w(const float* __restrict__ Wih, const float* __restrict__ Whh,
                          u16* __restrict__ whi, u16* __restrict__ wlo){
  long total = (long)NPAD_W * KP;
  for (long idx = (long)blockIdx.x*256 + threadIdx.x; idx < total; idx += (long)gridDim.x*256){
    int r = (int)(idx / KP), k = (int)(idx - (long)r*KP);
    float v = 0.f;
    if (k < Hd){
      if (r < 1200) v = Wih[(long)r*Hd + k];
      else if (r >= 1280 && r < 2480) v = Whh[(long)(r-1280)*Hd + k];
    }
    u16 hi = f2bf(v);
    whi[idx] = hi;
    wlo[idx] = f2bf(v - bf2f(hi));
  }
}

__global__ void k_setup_e(const float* __restrict__ emb, u16* __restrict__ ebf){
  long total = (long)NPAD_E * KP;
  for (long idx = (long)blockIdx.x*256 + threadIdx.x; idx < total; idx += (long)gridDim.x*256){
    long r = idx / KP; int k = (int)(idx - r*KP);
    float v = (r < Vv && k < Hd) ? emb[r*Hd + k] : 0.f;
    ebf[idx] = f2bf(v);
  }
}

__global__ void k_setup_xh(const float* __restrict__ ehid, const float* __restrict__ semb,
                           const int* __restrict__ didx, const int* __restrict__ sidx,
                           float* __restrict__ X, float* __restrict__ Hh, u16* __restrict__ Hbf){
  int m = blockIdx.x, k = threadIdx.x;   // 512 blocks x 448 threads
  Hbf[(long)m*KP + k] = 0;               // rows>=480 & cols>=400 stay 0 forever
  if (m < SBn){
    int s = m >> 4, b = m & 15;
    float xv = 0.f, hv = 0.f;
    if (k < Hd){
      xv = semb[(long)didx[s]*Hd + k] + semb[(long)sidx[s]*Hd + k];
      hv = ehid[(long)b*Hd + k];
    }
    X [(long)m*KP + k] = xv;
    Hh[(long)m*KP + k] = hv;
  }
}

// transpose Eo[b][l][k] -> EoT[b][k][l]
__global__ __launch_bounds__(256) void k_setup_t(const float* __restrict__ Eo, float* __restrict__ EoT){
  __shared__ float tile[64][65];
  int b = blockIdx.y;
  int kt = blockIdx.x / 8, lt = blockIdx.x - kt*8;
  int k0 = kt*64, l0 = lt*64;
  int c = threadIdx.x & 63, rb = threadIdx.x >> 6;
  #pragma unroll
  for (int p = 0; p < 16; ++p){
    int r = p*4 + rb;
    tile[r][c] = (k0 + c < Hd) ? Eo[((long)b*Ll + l0 + r)*Hd + k0 + c] : 0.f;
  }
  __syncthreads();
  #pragma unroll
  for (int p = 0; p < 16; ++p){
    int r = p*4 + rb;
    if (k0 + r < Hd) EoT[((long)b*Hd + k0 + r)*Ll + l0 + c] = tile[c][r];
  }
}

// ---------------- GRU GEMM (split bf16, 3 MFMAs) — R6 structure, untouched ----------------
__global__ __launch_bounds__(256) void k_ggemm(
    const float* __restrict__ X, const float* __restrict__ Hh,
    const u16* __restrict__ Bhi, const u16* __restrict__ Blo,
    float* __restrict__ Gm)
{
  __shared__ u16 As_hi[32*40], As_lo[32*40];
  __shared__ u16 Bs_hi[128*40], Bs_lo[128*40];
  int tid = threadIdx.x;
  int mt = blockIdx.x, yt = blockIdx.y;
  int seg = yt >= 10 ? 1 : 0, nt = seg ? yt-10 : yt;
  const float* A = seg ? Hh : X;
  int m0 = mt*32;
  long brow0 = (long)seg*1280 + (long)nt*128;
  int w = tid>>6, l = tid&63, lr = l&15, kg = l>>4;
  f4 acc[2][2] = {};
  int arow = tid>>3, ac4 = (tid&7)*4;
  int br4 = tid>>2, bc8 = (tid&3)*8;
  for (int ks = 0; ks < 14; ++ks){
    int k0 = ks*32;
    __syncthreads();
    { f4 v = *(const f4*)(A + (long)(m0+arow)*KP + k0 + ac4);
      u16 h0=f2bf(v.x),h1=f2bf(v.y),h2=f2bf(v.z),h3=f2bf(v.w);
      *(ushort4*)&As_hi[arow*40+ac4] = make_ushort4(h0,h1,h2,h3);
      u16 q0=f2bf(v.x-bf2f(h0)),q1=f2bf(v.y-bf2f(h1)),q2=f2bf(v.z-bf2f(h2)),q3=f2bf(v.w-bf2f(h3));
      *(ushort4*)&As_lo[arow*40+ac4] = make_ushort4(q0,q1,q2,q3);
    }
    #pragma unroll
    for (int p = 0; p < 2; ++p){
      long row = brow0 + p*64 + br4;
      *(uint4*)&Bs_hi[(p*64+br4)*40+bc8] = *(const uint4*)(Bhi + row*KP + k0 + bc8);
      *(uint4*)&Bs_lo[(p*64+br4)*40+bc8] = *(const uint4*)(Blo + row*KP + k0 + bc8);
    }
    __syncthreads();
    bf8 ah[2], al[2], bh[2], bl[2];
    #pragma unroll
    for (int i = 0; i < 2; ++i){
      ah[i] = *(const bf8*)&As_hi[(i*16+lr)*40 + kg*8];
      al[i] = *(const bf8*)&As_lo[(i*16+lr)*40 + kg*8];
    }
    #pragma unroll
    for (int j = 0; j < 2; ++j){
      int r = w*32 + j*16 + lr;
      bh[j] = *(const bf8*)&Bs_hi[r*40 + kg*8];
      bl[j] = *(const bf8*)&Bs_lo[r*40 + kg*8];
    }
    #pragma unroll
    for (int i = 0; i < 2; ++i)
      #pragma unroll
      for (int j = 0; j < 2; ++j){
        acc[i][j] = __builtin_amdgcn_mfma_f32_16x16x32_bf16(ah[i], bh[j], acc[i][j], 0,0,0);
        acc[i][j] = __builtin_amdgcn_mfma_f32_16x16x32_bf16(ah[i], bl[j], acc[i][j], 0,0,0);
        acc[i][j] = __builtin_amdgcn_mfma_f32_16x16x32_bf16(al[i], bh[j], acc[i][j], 0,0,0);
      }
  }
  #pragma unroll
  for (int i = 0; i < 2; ++i)
    #pragma unroll
    for (int j = 0; j < 2; ++j){
      int nl = nt*128 + w*32 + j*16 + lr;
      if (nl < 1200){
        int col = seg*1200 + nl;
        int mrow = m0 + i*16 + kg*4;
        #pragma unroll
        for (int r = 0; r < 4; ++r)
          Gm[(long)(mrow+r)*2400 + col] = acc[i][j][r];
      }
    }
}

// ---------------- fused GRU-combine + attention + p_gen (+gates), SG=2, shuffle reductions ----
__global__ __launch_bounds__(512) void k_attn(
    const float* __restrict__ Eo, const float* __restrict__ EoT, const int* __restrict__ cmask,
    const float* __restrict__ Gm, const float* __restrict__ bih, const float* __restrict__ bhh,
    float* __restrict__ Hh, u16* __restrict__ Hbf, const float* __restrict__ X,
    const float* __restrict__ wr, const float* __restrict__ wrb,
    const float* __restrict__ wg, const float* __restrict__ wgb,
    float* __restrict__ cp, float* __restrict__ pgen, float* __restrict__ og, int t)
{
  __shared__ float sh_h[SG][Hd];
  __shared__ float sh_c[SG][Hd];
  __shared__ float sh_p[SG][Ll];
  __shared__ float buf[4*SG*Ll];
  __shared__ float wred[2][SG*8];
  int tid = threadIdx.x, b = blockIdx.y, s0 = blockIdx.x*SG;
  int lane = tid & 63, wid = tid >> 6;

  // GRU combine for our SG rows
  for (int idx = tid; idx < SG*Hd; idx += 512){
    int sg = idx / Hd, j = idx - sg*Hd;
    long m = (long)(s0+sg)*B_ + b;
    const float* g = Gm + m*2400;
    float r = 1.f/(1.f+expf(-(g[j]     + bih[j]     + g[1200+j] + bhh[j])));
    float z = 1.f/(1.f+expf(-(g[400+j] + bih[400+j] + g[1600+j] + bhh[400+j])));
    float n = tanhf(g[800+j] + bih[800+j] + r*(g[2000+j] + bhh[800+j]));
    float h = (1.f-z)*n + z*Hh[m*KP + j];
    sh_h[sg][j] = h;
    Hh[m*KP + j] = h;
    Hbf[m*KP + j] = f2bf(h);
  }
  __syncthreads();

  // scores: thread = (lq=tid&127 -> l0=4*lq, kq=tid>>7), coalesced f4 reads of EoT
  {
    int lq = tid & 127, kq = tid >> 7;
    int l0 = lq*4;
    const float* ebase = EoT + (long)b*Hd*Ll;
    f4 sc[SG];
    #pragma unroll
    for (int sg = 0; sg < SG; ++sg) sc[sg] = f4{0.f,0.f,0.f,0.f};
    int k0 = kq*100;
    for (int k = k0; k < k0+100; k += 4){
      f4 h4[SG];
      #pragma unroll
      for (int sg = 0; sg < SG; ++sg) h4[sg] = *(const f4*)&sh_h[sg][k];
      #pragma unroll
      for (int kk = 0; kk < 4; ++kk){
        f4 e = *(const f4*)&ebase[(long)(k+kk)*Ll + l0];
        #pragma unroll
        for (int sg = 0; sg < SG; ++sg){
          float hk = h4[sg][kk];
          sc[sg].x += e.x*hk; sc[sg].y += e.y*hk; sc[sg].z += e.z*hk; sc[sg].w += e.w*hk;
        }
      }
    }
    #pragma unroll
    for (int sg = 0; sg < SG; ++sg)
      *(f4*)&buf[(kq*SG+sg)*Ll + l0] = sc[sg];
  }
  __syncthreads();

  // combine partials, mask; softmax via wave shuffle + 8-entry cross-wave combine
  float v[SG];
  {
    bool mok = cmask[b*Ll + tid] != 0;
    #pragma unroll
    for (int sg = 0; sg < SG; ++sg){
      float x = buf[sg*Ll+tid] + buf[(SG+sg)*Ll+tid] + buf[(2*SG+sg)*Ll+tid] + buf[(3*SG+sg)*Ll+tid];
      v[sg] = mok ? x : -INF;
    }
  }
  #pragma unroll
  for (int sg = 0; sg < SG; ++sg){
    float m_ = v[sg];
    #pragma unroll
    for (int d = 1; d < 64; d <<= 1) m_ = fmaxf(m_, __shfl_xor(m_, d));
    if (lane == 0) wred[0][sg*8 + wid] = m_;
  }
  __syncthreads();
  float p[SG];
  #pragma unroll
  for (int sg = 0; sg < SG; ++sg){
    float mx = wred[0][sg*8];
    #pragma unroll
    for (int q = 1; q < 8; ++q) mx = fmaxf(mx, wred[0][sg*8+q]);
    p[sg] = expf(v[sg] - mx);
    float s_ = p[sg];
    #pragma unroll
    for (int d = 1; d < 64; d <<= 1) s_ += __shfl_xor(s_, d);
    if (lane == 0) wred[1][sg*8 + wid] = s_;
  }
  __syncthreads();
  #pragma unroll
  for (int sg = 0; sg < SG; ++sg){
    float sum = 0.f;
    #pragma unroll
    for (int q = 0; q < 8; ++q) sum += wred[1][sg*8+q];
    float pp = p[sg] / sum;
    sh_p[sg][tid] = pp;
    cp[((long)(s0+sg)*B_ + b)*Ll + tid] = pp;
  }
  __syncthreads();

  // ctx: thread = (k4 = tid&127 [<100 active], lq = tid>>7)
  {
    int k4 = tid & 127, lq = tid >> 7;
    if (k4 < 100){
      int k = k4*4;
      f4 cacc[SG];
      #pragma unroll
      for (int sg = 0; sg < SG; ++sg) cacc[sg] = f4{0.f,0.f,0.f,0.f};
      for (int li = 0; li < 128; li += 4){
        int l2 = lq*128 + li;
        f4 pv[SG];
        #pragma unroll
        for (int sg = 0; sg < SG; ++sg) pv[sg] = *(const f4*)&sh_p[sg][l2];
        #pragma unroll
        for (int jj = 0; jj < 4; ++jj){
          f4 e = *(const f4*)&Eo[((long)b*Ll + l2 + jj)*Hd + k];
          #pragma unroll
          for (int sg = 0; sg < SG; ++sg){
            float pw = pv[sg][jj];
            cacc[sg].x += e.x*pw; cacc[sg].y += e.y*pw; cacc[sg].z += e.z*pw; cacc[sg].w += e.w*pw;
          }
        }
      }
      #pragma unroll
      for (int sg = 0; sg < SG; ++sg)
        *(f4*)&buf[(lq*SG+sg)*Hd + k] = cacc[sg];
    }
  }
  __syncthreads();
  if (tid < Hd){
    #pragma unroll
    for (int sg = 0; sg < SG; ++sg)
      sh_c[sg][tid] = buf[sg*Hd+tid] + buf[(SG+sg)*Hd+tid] + buf[(2*SG+sg)*Hd+tid] + buf[(3*SG+sg)*Hd+tid];
  }
  __syncthreads();

  // p_gen = sigmoid([h,c,x].wr + b)  (shuffle + 8-entry combine)
  {
    float part[SG];
    #pragma unroll
    for (int sg = 0; sg < SG; ++sg) part[sg] = 0.f;
    for (int j = tid; j < 1200; j += 512){
      float wv = wr[j];
      #pragma unroll
      for (int sg = 0; sg < SG; ++sg){
        float xv;
        if (j < 400) xv = sh_h[sg][j];
        else if (j < 800) xv = sh_c[sg][j-400];
        else xv = X[((long)(s0+sg)*B_ + b)*KP + (j-800)];
        part[sg] += xv*wv;
      }
    }
    #pragma unroll
    for (int sg = 0; sg < SG; ++sg){
      float s_ = part[sg];
      #pragma unroll
      for (int d = 1; d < 64; d <<= 1) s_ += __shfl_xor(s_, d);
      if (lane == 0) wred[0][sg*8 + wid] = s_;
    }
    __syncthreads();
    if (tid < SG){
      float sum = 0.f;
      #pragma unroll
      for (int q = 0; q < 8; ++q) sum += wred[0][tid*8+q];
      pgen[(long)(s0+tid)*B_ + b] = 1.f/(1.f+expf(-(sum + wrb[0])));
    }
  }

  // gates logits at t==0
  if (t == 0){
    for (int g = 0; g < Gg; ++g){
      float pt[SG];
      #pragma unroll
      for (int sg = 0; sg < SG; ++sg) pt[sg] = 0.f;
      if (tid < Hd){
        float wv = wg[g*Hd + tid];
        #pragma unroll
        for (int sg = 0; sg < SG; ++sg) pt[sg] = sh_c[sg][tid]*wv;
      }
      __syncthreads();   // protect wred[1] reuse across g iterations
      #pragma unroll
      for (int sg = 0; sg < SG; ++sg){
        float s_ = pt[sg];
        #pragma unroll
        for (int d = 1; d < 64; d <<= 1) s_ += __shfl_xor(s_, d);
        if (lane == 0) wred[1][sg*8 + wid] = s_;
      }
      __syncthreads();
      if (tid < SG){
        float sum = 0.f;
        #pragma unroll
        for (int q = 0; q < 8; ++q) sum += wred[1][tid*8+q];
        og[((long)b*S_ + (s0+tid))*Gg + g] = sum + wgb[g];
      }
    }
  }
}

// ---------------- vocab GEMM — R6 structure; mt=3 starts at 352 (skip zero-pad rows) ----------
// grid (141, 4): x = n-stripe (128 cols), y = m-tile: m0 in {0,128,256,352}
__global__ __launch_bounds__(256) void k_vgemm(
    const u16* __restrict__ Abf, const u16* __restrict__ Bhi,
    u16* __restrict__ E, float* __restrict__ pmax, float* __restrict__ psum)
{
  __shared__ u16 As[128*40], Bs[128*40];
  __shared__ float redm[2][128], reds[2][128];
  int tid = threadIdx.x;
  int ns = blockIdx.x, mt = blockIdx.y;
  int m0 = (mt == 3) ? 352 : mt*128;   // rows 352-383 duplicated by mt=2: bitwise-identical writes
  long brow0 = (long)ns*128;
  int w = tid>>6, l = tid&63, lr = l&15, kg = l>>4;
  int wm = w>>1, wn = w&1;
  int srow = tid>>1, sc8 = (tid&1)*16;
  const u16* aP = Abf + (long)(m0+srow)*KP + sc8;
  const u16* bP = Bhi + (brow0+srow)*KP + sc8;
  int so = srow*40 + sc8;
  f4 acc[4][4] = {};
  for (int ks = 0; ks < 14; ++ks){
    int k0 = ks*32;
    __syncthreads();
    *(uint4*)&As[so]     = *(const uint4*)(aP + k0);
    *(uint4*)&As[so + 8] = *(const uint4*)(aP + k0 + 8);
    *(uint4*)&Bs[so]     = *(const uint4*)(bP + k0);
    *(uint4*)&Bs[so + 8] = *(const uint4*)(bP + k0 + 8);
    __syncthreads();
    bf8 a[4], b[4];
    #pragma unroll
    for (int i = 0; i < 4; ++i) a[i] = *(const bf8*)&As[(wm*64 + i*16 + lr)*40 + kg*8];
    #pragma unroll
    for (int j = 0; j < 4; ++j) b[j] = *(const bf8*)&Bs[(wn*64 + j*16 + lr)*40 + kg*8];
    #pragma unroll
    for (int i = 0; i < 4; ++i)
      #pragma unroll
      for (int j = 0; j < 4; ++j)
        acc[i][j] = __builtin_amdgcn_mfma_f32_16x16x32_bf16(a[i], b[j], acc[i][j], 0,0,0);
  }
  // epilogue: per-row stripe max
  #pragma unroll
  for (int i = 0; i < 4; ++i)
    #pragma unroll
    for (int r = 0; r < 4; ++r){
      float mxv = -INF;
      #pragma unroll
      for (int j = 0; j < 4; ++j){
        int col = (int)brow0 + wn*64 + j*16 + lr;
        if (col < Vv) mxv = fmaxf(mxv, acc[i][j][r]);
      }
      #pragma unroll
      for (int d = 1; d < 16; d <<= 1) mxv = fmaxf(mxv, __shfl_xor(mxv, d));
      if (lr == 0) redm[wn][wm*64 + i*16 + kg*4 + r] = mxv;
    }
  __syncthreads();
  // exp, store bf16 E, per-row sums
  #pragma unroll
  for (int i = 0; i < 4; ++i)
    #pragma unroll
    for (int r = 0; r < 4; ++r){
      int rl = wm*64 + i*16 + kg*4 + r;
      float cmx = fmaxf(redm[0][rl], redm[1][rl]);
      float ssum = 0.f;
      long erow = (long)(m0 + rl)*EW;
      #pragma unroll
      for (int j = 0; j < 4; ++j){
        int col = (int)brow0 + wn*64 + j*16 + lr;
        float e = (col < Vv) ? expf(acc[i][j][r] - cmx) : 0.f;
        E[erow + col] = f2bf(e);
        ssum += e;
      }
      #pragma unroll
      for (int d = 1; d < 16; d <<= 1) ssum += __shfl_xor(ssum, d);
      if (lr == 0) reds[wn][rl] = ssum;
    }
  __syncthreads();
  if (tid < 128){
    pmax[(long)(m0+tid)*NST + ns] = fmaxf(redm[0][tid], redm[1][tid]);
    psum[(long)(m0+tid)*NST + ns] = reds[0][tid] + reds[1][tid];
  }
}

// ---------------- fused: LSE-combine + finalize + scatter + argmax + greedy feedback ----------
__global__ __launch_bounds__(512) void k_final(
    const u16* __restrict__ E, const float* __restrict__ pmax, const float* __restrict__ psum,
    const float* __restrict__ pgen, const float* __restrict__ cp,
    const int* __restrict__ cidx, const int* __restrict__ cmask,
    const float* __restrict__ emb, float* __restrict__ out, float* __restrict__ X, int t)
{
  __shared__ float scat[Vv];
  __shared__ float scale[NST];
  __shared__ float am[256], asum[256];
  __shared__ float rv[512];
  __shared__ int   ri[512];
  int tid = threadIdx.x, m = blockIdx.x;
  int b = m & 15, s = m >> 4;
  if (tid < 256){
    am[tid]   = tid < NST ? pmax[(long)m*NST + tid] : -1e30f;
    asum[tid] = tid < NST ? psum[(long)m*NST + tid] : 0.f;
  }
  for (int i = tid; i < Vv; i += 512) scat[i] = 0.f;
  __syncthreads();
  for (int o = 128; o > 0; o >>= 1){
    if (tid < o){
      float m2 = am[tid+o], M = fmaxf(am[tid], m2);
      asum[tid] = asum[tid]*expf(am[tid]-M) + asum[tid+o]*expf(m2-M);
      am[tid] = M;
    }
    __syncthreads();
  }
  float gmx = am[0], pg = pgen[m];
  float sc0 = pg / asum[0];
  if (tid < NST) scale[tid] = sc0 * expf(pmax[(long)m*NST + tid] - gmx);
  if (cmask[b*Ll + tid]){
    float vv = (1.f - pg)*cp[(long)m*Ll + tid];
    atomicAdd(&scat[cidx[b*Ll + tid]], vv);
  }
  __syncthreads();
  long eb = (long)m*EW;
  long ob = ((long)(b*S_ + s)*Tt + t)*(long)Vv;
  float bv = -1.f; int bi = 0;
  for (int i = tid; i < Vv/8; i += 512){
    u16x8 ev = *(const u16x8*)&E[eb + i*8];
    float sc = scale[(i*8) >> 7];
    f4 s0 = *(const f4*)&scat[i*8];
    f4 s1 = *(const f4*)&scat[i*8 + 4];
    f4 o0, o1;
    o0.x = sc*bf2f(ev[0]) + s0.x; o0.y = sc*bf2f(ev[1]) + s0.y;
    o0.z = sc*bf2f(ev[2]) + s0.z; o0.w = sc*bf2f(ev[3]) + s0.w;
    o1.x = sc*bf2f(ev[4]) + s1.x; o1.y = sc*bf2f(ev[5]) + s1.y;
    o1.z = sc*bf2f(ev[6]) + s1.z; o1.w = sc*bf2f(ev[7]) + s1.w;
    *(f4*)&out[ob + i*8]     = o0;
    *(f4*)&out[ob + i*8 + 4] = o1;
    int n0 = i*8;
    if (o0.x > bv){ bv = o0.x; bi = n0;   }
    if (o0.y > bv){ bv = o0.y; bi = n0+1; }
    if (o0.z > bv){ bv = o0.z; bi = n0+2; }
    if (o0.w > bv){ bv = o0.w; bi = n0+3; }
    if (o1.x > bv){ bv = o1.x; bi = n0+4; }
    if (o1.y > bv){ bv = o1.y; bi = n0+5; }
    if (o1.z > bv){ bv = o1.z; bi = n0+6; }
    if (o1.w > bv){ bv = o1.w; bi = n0+7; }
  }
  rv[tid] = bv; ri[tid] = bi;
  __syncthreads();
  for (int o = 256; o > 0; o >>= 1){
    if (tid < o){
      float v2 = rv[tid+o]; int i2 = ri[tid+o];
      if (v2 > rv[tid] || (v2 == rv[tid] && i2 < ri[tid])){ rv[tid] = v2; ri[tid] = i2; }
    }
    __syncthreads();
  }
  int win = ri[0];
  if (tid < Hd) X[(long)m*KP + tid] = emb[(long)win*Hd + tid];
}

// ---------------- launcher ----------------
extern "C" void kernel_launch(void* const* d_in, const int* in_sizes, int n_in,
                              void* d_out, int out_size, void* d_ws, size_t ws_size,
                              hipStream_t stream)
{
  const float* ehid  = (const float*)d_in[0];
  const float* eout  = (const float*)d_in[1];
  const int*   cidx  = (const int*)d_in[2];
  const int*   cmask = (const int*)d_in[3];
  const float* emb   = (const float*)d_in[5];
  const float* semb  = (const float*)d_in[6];
  const int*   didx  = (const int*)d_in[7];
  const int*   sidx  = (const int*)d_in[8];
  const float* Wih   = (const float*)d_in[9];
  const float* Whh   = (const float*)d_in[10];
  const float* bih   = (const float*)d_in[11];
  const float* bhh   = (const float*)d_in[12];
  const float* wr    = (const float*)d_in[13];
  const float* wrb   = (const float*)d_in[14];
  const float* wg    = (const float*)d_in[15];
  const float* wgb   = (const float*)d_in[16];
  float* out = (float*)d_out;

  char* ws = (char*)d_ws;
  u16*   ws_hi = (u16*)(ws + 0);            //  2,293,760
  u16*   ws_lo = (u16*)(ws + 2293760);      //  2,293,760
  u16*   ebf   = (u16*)(ws + 4587520);      // 16,285,696
  float* EoT   = (float*)(ws + 20873216);   // 13,107,200
  float* X     = (float*)(ws + 33980416);   //    860,160
  float* Hh    = (float*)(ws + 34840576);   //    860,160
  u16*   Hbf   = (u16*)(ws + 35700736);     //    458,752 (512 rows)
  float* Gm    = (float*)(ws + 36159488);   //  4,608,000
  u16*   E     = (u16*)(ws + 40767488);     // 18,481,152 (512 x 18048 bf16)
  float* cp    = (float*)(ws + 59248640);   //    983,040
  float* pg    = (float*)(ws + 60231680);   //      2,048
  float* pmax  = (float*)(ws + 60233728);   //    288,768
  float* psum  = (float*)(ws + 60522496);   //    288,768
  float* og = out + (long)B_*S_*Tt*Vv;

  k_setup_w <<<4480, 256, 0, stream>>>(Wih, Whh, ws_hi, ws_lo);
  k_setup_e <<<4096, 256, 0, stream>>>(emb, ebf);
  k_setup_xh<<<512, 448, 0, stream>>>(ehid, semb, didx, sidx, X, Hh, Hbf);
  k_setup_t <<<dim3(56,16), 256, 0, stream>>>(eout, EoT);

  for (int t = 0; t < Tt; ++t){
    k_ggemm <<<dim3(15,20), 256, 0, stream>>>(X, Hh, ws_hi, ws_lo, Gm);
    k_attn  <<<dim3(15,16), 512, 0, stream>>>(eout, EoT, cmask, Gm, bih, bhh, Hh, Hbf, X,
                                              wr, wrb, wg, wgb, cp, pg, og, t);
    k_vgemm <<<dim3(141,4), 256, 0, stream>>>(Hbf, ebf, E, pmax, psum);
    k_final <<<480, 512, 0, stream>>>(E, pmax, psum, pg, cp, cidx, cmask, emb, out, X, t);
  }
}

// Round 13
// 889.302 us; speedup vs baseline: 1.2554x; 1.1287x over previous
//
#include <hip/hip_runtime.h>
#include <hip/hip_bf16.h>

#define S_  30
#define B_  16
#define Hd  400
#define Vv  18000
#define Ll  512
#define Gg  3
#define Tt  10
#define SBn 480
#define KP  448      // K padded to 14*32
#define NPAD_W 2560
#define NPAD_E 18176
#define NST 141      // vocab N-stripes of 128
#define SG  2        // slots per k_attn block
#define EW  18048    // E row stride

typedef unsigned short u16;
typedef __attribute__((ext_vector_type(8))) short bf8;
typedef __attribute__((ext_vector_type(8))) unsigned short u16x8;
typedef __attribute__((ext_vector_type(4))) float f4;

#define INF __builtin_inff()

__device__ __forceinline__ u16 f2bf(float f){
  union { __hip_bfloat16 h; u16 u; } c;
  c.h = __float2bfloat16(f);
  return c.u;
}
__device__ __forceinline__ float bf2f(u16 x){
  union { u16 u; __hip_bfloat16 h; } c;
  c.u = x;
  return __bfloat162float(c.h);
}

// ---------------- setup kernels ----------------

__global__ void k_setup_w(const float* __restrict__ Wih, const float* __restrict__ Whh,
                          u16* __restrict__ whi, u16* __restrict__ wlo){
  long total = (long)NPAD_W * KP;
  for (long idx = (long)blockIdx.x*256 + threadIdx.x; idx < total; idx += (long)gridDim.x*256){
    int r = (int)(idx / KP), k = (int)(idx - (long)r*KP);
    float v = 0.f;
    if (k < Hd){
      if (r < 1200) v = Wih[(long)r*Hd + k];
      else if (r >= 1280 && r < 2480) v = Whh[(long)(r-1280)*Hd + k];
    }
    u16 hi = f2bf(v);
    whi[idx] = hi;
    wlo[idx] = f2bf(v - bf2f(hi));
  }
}

__global__ void k_setup_e(const float* __restrict__ emb, u16* __restrict__ ebf){
  long total = (long)NPAD_E * KP;
  for (long idx = (long)blockIdx.x*256 + threadIdx.x; idx < total; idx += (long)gridDim.x*256){
    long r = idx / KP; int k = (int)(idx - r*KP);
    float v = (r < Vv && k < Hd) ? emb[r*Hd + k] : 0.f;
    ebf[idx] = f2bf(v);
  }
}

__global__ void k_setup_xh(const float* __restrict__ ehid, const float* __restrict__ semb,
                           const int* __restrict__ didx, const int* __restrict__ sidx,
                           float* __restrict__ X, float* __restrict__ Hh, u16* __restrict__ Hbf){
  int m = blockIdx.x, k = threadIdx.x;   // 512 blocks x 448 threads
  Hbf[(long)m*KP + k] = 0;               // rows>=480 & cols>=400 stay 0 forever
  if (m < SBn){
    int s = m >> 4, b = m & 15;
    float xv = 0.f, hv = 0.f;
    if (k < Hd){
      xv = semb[(long)didx[s]*Hd + k] + semb[(long)sidx[s]*Hd + k];
      hv = ehid[(long)b*Hd + k];
    }
    X [(long)m*KP + k] = xv;
    Hh[(long)m*KP + k] = hv;
  }
}

// transpose Eo[b][l][k] -> EoT[b][k][l]
__global__ __launch_bounds__(256) void k_setup_t(const float* __restrict__ Eo, float* __restrict__ EoT){
  __shared__ float tile[64][65];
  int b = blockIdx.y;
  int kt = blockIdx.x / 8, lt = blockIdx.x - kt*8;
  int k0 = kt*64, l0 = lt*64;
  int c = threadIdx.x & 63, rb = threadIdx.x >> 6;
  #pragma unroll
  for (int p = 0; p < 16; ++p){
    int r = p*4 + rb;
    tile[r][c] = (k0 + c < Hd) ? Eo[((long)b*Ll + l0 + r)*Hd + k0 + c] : 0.f;
  }
  __syncthreads();
  #pragma unroll
  for (int p = 0; p < 16; ++p){
    int r = p*4 + rb;
    if (k0 + r < Hd) EoT[((long)b*Hd + k0 + r)*Ll + l0 + c] = tile[c][r];
  }
}

// ---------------- GRU GEMM (split bf16, 3 MFMAs) — R6 structure, untouched ----------------
__global__ __launch_bounds__(256) void k_ggemm(
    const float* __restrict__ X, const float* __restrict__ Hh,
    const u16* __restrict__ Bhi, const u16* __restrict__ Blo,
    float* __restrict__ Gm)
{
  __shared__ u16 As_hi[32*40], As_lo[32*40];
  __shared__ u16 Bs_hi[128*40], Bs_lo[128*40];
  int tid = threadIdx.x;
  int mt = blockIdx.x, yt = blockIdx.y;
  int seg = yt >= 10 ? 1 : 0, nt = seg ? yt-10 : yt;
  const float* A = seg ? Hh : X;
  int m0 = mt*32;
  long brow0 = (long)seg*1280 + (long)nt*128;
  int w = tid>>6, l = tid&63, lr = l&15, kg = l>>4;
  f4 acc[2][2] = {};
  int arow = tid>>3, ac4 = (tid&7)*4;
  int br4 = tid>>2, bc8 = (tid&3)*8;
  for (int ks = 0; ks < 14; ++ks){
    int k0 = ks*32;
    __syncthreads();
    { f4 v = *(const f4*)(A + (long)(m0+arow)*KP + k0 + ac4);
      u16 h0=f2bf(v.x),h1=f2bf(v.y),h2=f2bf(v.z),h3=f2bf(v.w);
      *(ushort4*)&As_hi[arow*40+ac4] = make_ushort4(h0,h1,h2,h3);
      u16 q0=f2bf(v.x-bf2f(h0)),q1=f2bf(v.y-bf2f(h1)),q2=f2bf(v.z-bf2f(h2)),q3=f2bf(v.w-bf2f(h3));
      *(ushort4*)&As_lo[arow*40+ac4] = make_ushort4(q0,q1,q2,q3);
    }
    #pragma unroll
    for (int p = 0; p < 2; ++p){
      long row = brow0 + p*64 + br4;
      *(uint4*)&Bs_hi[(p*64+br4)*40+bc8] = *(const uint4*)(Bhi + row*KP + k0 + bc8);
      *(uint4*)&Bs_lo[(p*64+br4)*40+bc8] = *(const uint4*)(Blo + row*KP + k0 + bc8);
    }
    __syncthreads();
    bf8 ah[2], al[2], bh[2], bl[2];
    #pragma unroll
    for (int i = 0; i < 2; ++i){
      ah[i] = *(const bf8*)&As_hi[(i*16+lr)*40 + kg*8];
      al[i] = *(const bf8*)&As_lo[(i*16+lr)*40 + kg*8];
    }
    #pragma unroll
    for (int j = 0; j < 2; ++j){
      int r = w*32 + j*16 + lr;
      bh[j] = *(const bf8*)&Bs_hi[r*40 + kg*8];
      bl[j] = *(const bf8*)&Bs_lo[r*40 + kg*8];
    }
    #pragma unroll
    for (int i = 0; i < 2; ++i)
      #pragma unroll
      for (int j = 0; j < 2; ++j){
        acc[i][j] = __builtin_amdgcn_mfma_f32_16x16x32_bf16(ah[i], bh[j], acc[i][j], 0,0,0);
        acc[i][j] = __builtin_amdgcn_mfma_f32_16x16x32_bf16(ah[i], bl[j], acc[i][j], 0,0,0);
        acc[i][j] = __builtin_amdgcn_mfma_f32_16x16x32_bf16(al[i], bh[j], acc[i][j], 0,0,0);
      }
  }
  #pragma unroll
  for (int i = 0; i < 2; ++i)
    #pragma unroll
    for (int j = 0; j < 2; ++j){
      int nl = nt*128 + w*32 + j*16 + lr;
      if (nl < 1200){
        int col = seg*1200 + nl;
        int mrow = m0 + i*16 + kg*4;
        #pragma unroll
        for (int r = 0; r < 4; ++r)
          Gm[(long)(mrow+r)*2400 + col] = acc[i][j][r];
      }
    }
}

// ---------------- fused GRU-combine + attention + p_gen (+gates), SG=2, shuffle reductions ----
// grid (16, 15): x = b (xcd = b%8 under round-robin -> per-XCD L2 holds 2 b's of Eo/EoT), y = s-group
__global__ __launch_bounds__(512) void k_attn(
    const float* __restrict__ Eo, const float* __restrict__ EoT, const int* __restrict__ cmask,
    const float* __restrict__ Gm, const float* __restrict__ bih, const float* __restrict__ bhh,
    float* __restrict__ Hh, u16* __restrict__ Hbf, const float* __restrict__ X,
    const float* __restrict__ wr, const float* __restrict__ wrb,
    const float* __restrict__ wg, const float* __restrict__ wgb,
    float* __restrict__ cp, float* __restrict__ pgen, float* __restrict__ og, int t)
{
  __shared__ float sh_h[SG][Hd];
  __shared__ float sh_c[SG][Hd];
  __shared__ float sh_p[SG][Ll];
  __shared__ float buf[4*SG*Ll];
  __shared__ float wred[2][SG*8];
  int tid = threadIdx.x, b = blockIdx.x, s0 = blockIdx.y*SG;
  int lane = tid & 63, wid = tid >> 6;

  // GRU combine for our SG rows
  for (int idx = tid; idx < SG*Hd; idx += 512){
    int sg = idx / Hd, j = idx - sg*Hd;
    long m = (long)(s0+sg)*B_ + b;
    const float* g = Gm + m*2400;
    float r = 1.f/(1.f+expf(-(g[j]     + bih[j]     + g[1200+j] + bhh[j])));
    float z = 1.f/(1.f+expf(-(g[400+j] + bih[400+j] + g[1600+j] + bhh[400+j])));
    float n = tanhf(g[800+j] + bih[800+j] + r*(g[2000+j] + bhh[800+j]));
    float h = (1.f-z)*n + z*Hh[m*KP + j];
    sh_h[sg][j] = h;
    Hh[m*KP + j] = h;
    Hbf[m*KP + j] = f2bf(h);
  }
  __syncthreads();

  // scores: thread = (lq=tid&127 -> l0=4*lq, kq=tid>>7), coalesced f4 reads of EoT
  {
    int lq = tid & 127, kq = tid >> 7;
    int l0 = lq*4;
    const float* ebase = EoT + (long)b*Hd*Ll;
    f4 sc[SG];
    #pragma unroll
    for (int sg = 0; sg < SG; ++sg) sc[sg] = f4{0.f,0.f,0.f,0.f};
    int k0 = kq*100;
    for (int k = k0; k < k0+100; k += 4){
      f4 h4[SG];
      #pragma unroll
      for (int sg = 0; sg < SG; ++sg) h4[sg] = *(const f4*)&sh_h[sg][k];
      #pragma unroll
      for (int kk = 0; kk < 4; ++kk){
        f4 e = *(const f4*)&ebase[(long)(k+kk)*Ll + l0];
        #pragma unroll
        for (int sg = 0; sg < SG; ++sg){
          float hk = h4[sg][kk];
          sc[sg].x += e.x*hk; sc[sg].y += e.y*hk; sc[sg].z += e.z*hk; sc[sg].w += e.w*hk;
        }
      }
    }
    #pragma unroll
    for (int sg = 0; sg < SG; ++sg)
      *(f4*)&buf[(kq*SG+sg)*Ll + l0] = sc[sg];
  }
  __syncthreads();

  // combine partials, mask; softmax via wave shuffle + 8-entry cross-wave combine
  float v[SG];
  {
    bool mok = cmask[b*Ll + tid] != 0;
    #pragma unroll
    for (int sg = 0; sg < SG; ++sg){
      float x = buf[sg*Ll+tid] + buf[(SG+sg)*Ll+tid] + buf[(2*SG+sg)*Ll+tid] + buf[(3*SG+sg)*Ll+tid];
      v[sg] = mok ? x : -INF;
    }
  }
  #pragma unroll
  for (int sg = 0; sg < SG; ++sg){
    float m_ = v[sg];
    #pragma unroll
    for (int d = 1; d < 64; d <<= 1) m_ = fmaxf(m_, __shfl_xor(m_, d));
    if (lane == 0) wred[0][sg*8 + wid] = m_;
  }
  __syncthreads();
  float p[SG];
  #pragma unroll
  for (int sg = 0; sg < SG; ++sg){
    float mx = wred[0][sg*8];
    #pragma unroll
    for (int q = 1; q < 8; ++q) mx = fmaxf(mx, wred[0][sg*8+q]);
    p[sg] = expf(v[sg] - mx);
    float s_ = p[sg];
    #pragma unroll
    for (int d = 1; d < 64; d <<= 1) s_ += __shfl_xor(s_, d);
    if (lane == 0) wred[1][sg*8 + wid] = s_;
  }
  __syncthreads();
  #pragma unroll
  for (int sg = 0; sg < SG; ++sg){
    float sum = 0.f;
    #pragma unroll
    for (int q = 0; q < 8; ++q) sum += wred[1][sg*8+q];
    float pp = p[sg] / sum;
    sh_p[sg][tid] = pp;
    cp[((long)(s0+sg)*B_ + b)*Ll + tid] = pp;
  }
  __syncthreads();

  // ctx: thread = (k4 = tid&127 [<100 active], lq = tid>>7)
  {
    int k4 = tid & 127, lq = tid >> 7;
    if (k4 < 100){
      int k = k4*4;
      f4 cacc[SG];
      #pragma unroll
      for (int sg = 0; sg < SG; ++sg) cacc[sg] = f4{0.f,0.f,0.f,0.f};
      for (int li = 0; li < 128; li += 4){
        int l2 = lq*128 + li;
        f4 pv[SG];
        #pragma unroll
        for (int sg = 0; sg < SG; ++sg) pv[sg] = *(const f4*)&sh_p[sg][l2];
        #pragma unroll
        for (int jj = 0; jj < 4; ++jj){
          f4 e = *(const f4*)&Eo[((long)b*Ll + l2 + jj)*Hd + k];
          #pragma unroll
          for (int sg = 0; sg < SG; ++sg){
            float pw = pv[sg][jj];
            cacc[sg].x += e.x*pw; cacc[sg].y += e.y*pw; cacc[sg].z += e.z*pw; cacc[sg].w += e.w*pw;
          }
        }
      }
      #pragma unroll
      for (int sg = 0; sg < SG; ++sg)
        *(f4*)&buf[(lq*SG+sg)*Hd + k] = cacc[sg];
    }
  }
  __syncthreads();
  if (tid < Hd){
    #pragma unroll
    for (int sg = 0; sg < SG; ++sg)
      sh_c[sg][tid] = buf[sg*Hd+tid] + buf[(SG+sg)*Hd+tid] + buf[(2*SG+sg)*Hd+tid] + buf[(3*SG+sg)*Hd+tid];
  }
  __syncthreads();

  // p_gen = sigmoid([h,c,x].wr + b)  (shuffle + 8-entry combine)
  {
    float part[SG];
    #pragma unroll
    for (int sg = 0; sg < SG; ++sg) part[sg] = 0.f;
    for (int j = tid; j < 1200; j += 512){
      float wv = wr[j];
      #pragma unroll
      for (int sg = 0; sg < SG; ++sg){
        float xv;
        if (j < 400) xv = sh_h[sg][j];
        else if (j < 800) xv = sh_c[sg][j-400];
        else xv = X[((long)(s0+sg)*B_ + b)*KP + (j-800)];
        part[sg] += xv*wv;
      }
    }
    #pragma unroll
    for (int sg = 0; sg < SG; ++sg){
      float s_ = part[sg];
      #pragma unroll
      for (int d = 1; d < 64; d <<= 1) s_ += __shfl_xor(s_, d);
      if (lane == 0) wred[0][sg*8 + wid] = s_;
    }
    __syncthreads();
    if (tid < SG){
      float sum = 0.f;
      #pragma unroll
      for (int q = 0; q < 8; ++q) sum += wred[0][tid*8+q];
      pgen[(long)(s0+tid)*B_ + b] = 1.f/(1.f+expf(-(sum + wrb[0])));
    }
  }

  // gates logits at t==0
  if (t == 0){
    for (int g = 0; g < Gg; ++g){
      float pt[SG];
      #pragma unroll
      for (int sg = 0; sg < SG; ++sg) pt[sg] = 0.f;
      if (tid < Hd){
        float wv = wg[g*Hd + tid];
        #pragma unroll
        for (int sg = 0; sg < SG; ++sg) pt[sg] = sh_c[sg][tid]*wv;
      }
      __syncthreads();   // protect wred[1] reuse across g iterations
      #pragma unroll
      for (int sg = 0; sg < SG; ++sg){
        float s_ = pt[sg];
        #pragma unroll
        for (int d = 1; d < 64; d <<= 1) s_ += __shfl_xor(s_, d);
        if (lane == 0) wred[1][sg*8 + wid] = s_;
      }
      __syncthreads();
      if (tid < SG){
        float sum = 0.f;
        #pragma unroll
        for (int q = 0; q < 8; ++q) sum += wred[1][tid*8+q];
        og[((long)b*S_ + (s0+tid))*Gg + g] = sum + wgb[g];
      }
    }
  }
}

// ---------------- vocab GEMM — R6 structure; 1D grid remapped so the 4 mt-blocks of each
// B-stripe share an XCD (i%8 == ns%8 under round-robin) ----------
// grid 576: i -> c=i&7, j=i>>3, ns=c+8*(j>>2), mt=j&3; ns>=141 exits
__global__ __launch_bounds__(256) void k_vgemm(
    const u16* __restrict__ Abf, const u16* __restrict__ Bhi,
    u16* __restrict__ E, float* __restrict__ pmax, float* __restrict__ psum)
{
  __shared__ u16 As[128*40], Bs[128*40];
  __shared__ float redm[2][128], reds[2][128];
  int tid = threadIdx.x;
  int i = blockIdx.x;
  int cx = i & 7, j = i >> 3;
  int ns = cx + 8*(j >> 2);
  int mt = j & 3;
  if (ns >= NST) return;
  int m0 = (mt == 3) ? 352 : mt*128;   // rows 352-383 duplicated by mt=2: bitwise-identical writes
  long brow0 = (long)ns*128;
  int w = tid>>6, l = tid&63, lr = l&15, kg = l>>4;
  int wm = w>>1, wn = w&1;
  int srow = tid>>1, sc8 = (tid&1)*16;
  const u16* aP = Abf + (long)(m0+srow)*KP + sc8;
  const u16* bP = Bhi + (brow0+srow)*KP + sc8;
  int so = srow*40 + sc8;
  f4 acc[4][4] = {};
  for (int ks = 0; ks < 14; ++ks){
    int k0 = ks*32;
    __syncthreads();
    *(uint4*)&As[so]     = *(const uint4*)(aP + k0);
    *(uint4*)&As[so + 8] = *(const uint4*)(aP + k0 + 8);
    *(uint4*)&Bs[so]     = *(const uint4*)(bP + k0);
    *(uint4*)&Bs[so + 8] = *(const uint4*)(bP + k0 + 8);
    __syncthreads();
    bf8 a[4], b[4];
    #pragma unroll
    for (int ii = 0; ii < 4; ++ii) a[ii] = *(const bf8*)&As[(wm*64 + ii*16 + lr)*40 + kg*8];
    #pragma unroll
    for (int jj = 0; jj < 4; ++jj) b[jj] = *(const bf8*)&Bs[(wn*64 + jj*16 + lr)*40 + kg*8];
    #pragma unroll
    for (int ii = 0; ii < 4; ++ii)
      #pragma unroll
      for (int jj = 0; jj < 4; ++jj)
        acc[ii][jj] = __builtin_amdgcn_mfma_f32_16x16x32_bf16(a[ii], b[jj], acc[ii][jj], 0,0,0);
  }
  // epilogue: per-row stripe max
  #pragma unroll
  for (int ii = 0; ii < 4; ++ii)
    #pragma unroll
    for (int r = 0; r < 4; ++r){
      float mxv = -INF;
      #pragma unroll
      for (int jj = 0; jj < 4; ++jj){
        int col = (int)brow0 + wn*64 + jj*16 + lr;
        if (col < Vv) mxv = fmaxf(mxv, acc[ii][jj][r]);
      }
      #pragma unroll
      for (int d = 1; d < 16; d <<= 1) mxv = fmaxf(mxv, __shfl_xor(mxv, d));
      if (lr == 0) redm[wn][wm*64 + ii*16 + kg*4 + r] = mxv;
    }
  __syncthreads();
  // exp, store bf16 E, per-row sums
  #pragma unroll
  for (int ii = 0; ii < 4; ++ii)
    #pragma unroll
    for (int r = 0; r < 4; ++r){
      int rl = wm*64 + ii*16 + kg*4 + r;
      float cmx = fmaxf(redm[0][rl], redm[1][rl]);
      float ssum = 0.f;
      long erow = (long)(m0 + rl)*EW;
      #pragma unroll
      for (int jj = 0; jj < 4; ++jj){
        int col = (int)brow0 + wn*64 + jj*16 + lr;
        float e = (col < Vv) ? expf(acc[ii][jj][r] - cmx) : 0.f;
        E[erow + col] = f2bf(e);
        ssum += e;
      }
      #pragma unroll
      for (int d = 1; d < 16; d <<= 1) ssum += __shfl_xor(ssum, d);
      if (lr == 0) reds[wn][rl] = ssum;
    }
  __syncthreads();
  if (tid < 128){
    pmax[(long)(m0+tid)*NST + ns] = fmaxf(redm[0][tid], redm[1][tid]);
    psum[(long)(m0+tid)*NST + ns] = reds[0][tid] + reds[1][tid];
  }
}

// ---------------- fused: LSE-combine + finalize + scatter + argmax + greedy feedback ----------
__global__ __launch_bounds__(512) void k_final(
    const u16* __restrict__ E, const float* __restrict__ pmax, const float* __restrict__ psum,
    const float* __restrict__ pgen, const float* __restrict__ cp,
    const int* __restrict__ cidx, const int* __restrict__ cmask,
    const float* __restrict__ emb, float* __restrict__ out, float* __restrict__ X, int t)
{
  __shared__ float scat[Vv];
  __shared__ float scale[NST];
  __shared__ float am[256], asum[256];
  __shared__ float rv[512];
  __shared__ int   ri[512];
  int tid = threadIdx.x, m = blockIdx.x;
  int b = m & 15, s = m >> 4;
  if (tid < 256){
    am[tid]   = tid < NST ? pmax[(long)m*NST + tid] : -1e30f;
    asum[tid] = tid < NST ? psum[(long)m*NST + tid] : 0.f;
  }
  for (int i = tid; i < Vv; i += 512) scat[i] = 0.f;
  __syncthreads();
  for (int o = 128; o > 0; o >>= 1){
    if (tid < o){
      float m2 = am[tid+o], M = fmaxf(am[tid], m2);
      asum[tid] = asum[tid]*expf(am[tid]-M) + asum[tid+o]*expf(m2-M);
      am[tid] = M;
    }
    __syncthreads();
  }
  float gmx = am[0], pg = pgen[m];
  float sc0 = pg / asum[0];
  if (tid < NST) scale[tid] = sc0 * expf(pmax[(long)m*NST + tid] - gmx);
  if (cmask[b*Ll + tid]){
    float vv = (1.f - pg)*cp[(long)m*Ll + tid];
    atomicAdd(&scat[cidx[b*Ll + tid]], vv);
  }
  __syncthreads();
  long eb = (long)m*EW;
  long ob = ((long)(b*S_ + s)*Tt + t)*(long)Vv;
  float bv = -1.f; int bi = 0;
  for (int i = tid; i < Vv/8; i += 512){
    u16x8 ev = *(const u16x8*)&E[eb + i*8];
    float sc = scale[(i*8) >> 7];
    f4 s0 = *(const f4*)&scat[i*8];
    f4 s1 = *(const f4*)&scat[i*8 + 4];
    f4 o0, o1;
    o0.x = sc*bf2f(ev[0]) + s0.x; o0.y = sc*bf2f(ev[1]) + s0.y;
    o0.z = sc*bf2f(ev[2]) + s0.z; o0.w = sc*bf2f(ev[3]) + s0.w;
    o1.x = sc*bf2f(ev[4]) + s1.x; o1.y = sc*bf2f(ev[5]) + s1.y;
    o1.z = sc*bf2f(ev[6]) + s1.z; o1.w = sc*bf2f(ev[7]) + s1.w;
    *(f4*)&out[ob + i*8]     = o0;
    *(f4*)&out[ob + i*8 + 4] = o1;
    int n0 = i*8;
    if (o0.x > bv){ bv = o0.x; bi = n0;   }
    if (o0.y > bv){ bv = o0.y; bi = n0+1; }
    if (o0.z > bv){ bv = o0.z; bi = n0+2; }
    if (o0.w > bv){ bv = o0.w; bi = n0+3; }
    if (o1.x > bv){ bv = o1.x; bi = n0+4; }
    if (o1.y > bv){ bv = o1.y; bi = n0+5; }
    if (o1.z > bv){ bv = o1.z; bi = n0+6; }
    if (o1.w > bv){ bv = o1.w; bi = n0+7; }
  }
  rv[tid] = bv; ri[tid] = bi;
  __syncthreads();
  for (int o = 256; o > 0; o >>= 1){
    if (tid < o){
      float v2 = rv[tid+o]; int i2 = ri[tid+o];
      if (v2 > rv[tid] || (v2 == rv[tid] && i2 < ri[tid])){ rv[tid] = v2; ri[tid] = i2; }
    }
    __syncthreads();
  }
  int win = ri[0];
  if (tid < Hd) X[(long)m*KP + tid] = emb[(long)win*Hd + tid];
}

// ---------------- launcher ----------------
extern "C" void kernel_launch(void* const* d_in, const int* in_sizes, int n_in,
                              void* d_out, int out_size, void* d_ws, size_t ws_size,
                              hipStream_t stream)
{
  const float* ehid  = (const float*)d_in[0];
  const float* eout  = (const float*)d_in[1];
  const int*   cidx  = (const int*)d_in[2];
  const int*   cmask = (const int*)d_in[3];
  const float* emb   = (const float*)d_in[5];
  const float* semb  = (const float*)d_in[6];
  const int*   didx  = (const int*)d_in[7];
  const int*   sidx  = (const int*)d_in[8];
  const float* Wih   = (const float*)d_in[9];
  const float* Whh   = (const float*)d_in[10];
  const float* bih   = (const float*)d_in[11];
  const float* bhh   = (const float*)d_in[12];
  const float* wr    = (const float*)d_in[13];
  const float* wrb   = (const float*)d_in[14];
  const float* wg    = (const float*)d_in[15];
  const float* wgb   = (const float*)d_in[16];
  float* out = (float*)d_out;

  char* ws = (char*)d_ws;
  u16*   ws_hi = (u16*)(ws + 0);            //  2,293,760
  u16*   ws_lo = (u16*)(ws + 2293760);      //  2,293,760
  u16*   ebf   = (u16*)(ws + 4587520);      // 16,285,696
  float* EoT   = (float*)(ws + 20873216);   // 13,107,200
  float* X     = (float*)(ws + 33980416);   //    860,160
  float* Hh    = (float*)(ws + 34840576);   //    860,160
  u16*   Hbf   = (u16*)(ws + 35700736);     //    458,752 (512 rows)
  float* Gm    = (float*)(ws + 36159488);   //  4,608,000
  u16*   E     = (u16*)(ws + 40767488);     // 18,481,152 (512 x 18048 bf16)
  float* cp    = (float*)(ws + 59248640);   //    983,040
  float* pg    = (float*)(ws + 60231680);   //      2,048
  float* pmax  = (float*)(ws + 60233728);   //    288,768
  float* psum  = (float*)(ws + 60522496);   //    288,768
  float* og = out + (long)B_*S_*Tt*Vv;

  k_setup_w <<<4480, 256, 0, stream>>>(Wih, Whh, ws_hi, ws_lo);
  k_setup_e <<<4096, 256, 0, stream>>>(emb, ebf);
  k_setup_xh<<<512, 448, 0, stream>>>(ehid, semb, didx, sidx, X, Hh, Hbf);
  k_setup_t <<<dim3(56,16), 256, 0, stream>>>(eout, EoT);

  for (int t = 0; t < Tt; ++t){
    k_ggemm <<<dim3(15,20), 256, 0, stream>>>(X, Hh, ws_hi, ws_lo, Gm);
    k_attn  <<<dim3(16,15), 512, 0, stream>>>(eout, EoT, cmask, Gm, bih, bhh, Hh, Hbf, X,
                                              wr, wrb, wg, wgb, cp, pg, og, t);
    k_vgemm <<<576, 256, 0, stream>>>(Hbf, ebf, E, pmax, psum);
    k_final <<<480, 512, 0, stream>>>(E, pmax, psum, pg, cp, cidx, cmask, emb, out, X, t);
  }
}

// Round 14
// 870.067 us; speedup vs baseline: 1.2831x; 1.0221x over previous
//
#include <hip/hip_runtime.h>
#include <hip/hip_bf16.h>

#define S_  30
#define B_  16
#define Hd  400
#define Vv  18000
#define Ll  512
#define Gg  3
#define Tt  10
#define SBn 480
#define KP  448      // K padded to 14*32
#define NPAD_W 2560
#define NPAD_E 18176
#define NST 141      // vocab N-stripes of 128
#define SG  2        // slots per k_attn block
#define EW  18048    // E row stride

typedef unsigned short u16;
typedef __attribute__((ext_vector_type(8))) short bf8;
typedef __attribute__((ext_vector_type(8))) unsigned short u16x8;
typedef __attribute__((ext_vector_type(4))) float f4;

#define INF __builtin_inff()

__device__ __forceinline__ u16 f2bf(float f){
  union { __hip_bfloat16 h; u16 u; } c;
  c.h = __float2bfloat16(f);
  return c.u;
}
__device__ __forceinline__ float bf2f(u16 x){
  union { u16 u; __hip_bfloat16 h; } c;
  c.u = x;
  return __bfloat162float(c.h);
}

// ---------------- setup kernels ----------------

__global__ void k_setup_w(const float* __restrict__ Wih, const float* __restrict__ Whh,
                          u16* __restrict__ whi, u16* __restrict__ wlo){
  long total = (long)NPAD_W * KP;
  for (long idx = (long)blockIdx.x*256 + threadIdx.x; idx < total; idx += (long)gridDim.x*256){
    int r = (int)(idx / KP), k = (int)(idx - (long)r*KP);
    float v = 0.f;
    if (k < Hd){
      if (r < 1200) v = Wih[(long)r*Hd + k];
      else if (r >= 1280 && r < 2480) v = Whh[(long)(r-1280)*Hd + k];
    }
    u16 hi = f2bf(v);
    whi[idx] = hi;
    wlo[idx] = f2bf(v - bf2f(hi));
  }
}

__global__ void k_setup_e(const float* __restrict__ emb, u16* __restrict__ ebf){
  long total = (long)NPAD_E * KP;
  for (long idx = (long)blockIdx.x*256 + threadIdx.x; idx < total; idx += (long)gridDim.x*256){
    long r = idx / KP; int k = (int)(idx - r*KP);
    float v = (r < Vv && k < Hd) ? emb[r*Hd + k] : 0.f;
    ebf[idx] = f2bf(v);
  }
}

__global__ void k_setup_xh(const float* __restrict__ ehid, const float* __restrict__ semb,
                           const int* __restrict__ didx, const int* __restrict__ sidx,
                           float* __restrict__ X, float* __restrict__ Hh, u16* __restrict__ Hbf){
  int m = blockIdx.x, k = threadIdx.x;   // 512 blocks x 448 threads
  Hbf[(long)m*KP + k] = 0;               // rows>=480 & cols>=400 stay 0 forever
  if (m < SBn){
    int s = m >> 4, b = m & 15;
    float xv = 0.f, hv = 0.f;
    if (k < Hd){
      xv = semb[(long)didx[s]*Hd + k] + semb[(long)sidx[s]*Hd + k];
      hv = ehid[(long)b*Hd + k];
    }
    X [(long)m*KP + k] = xv;
    Hh[(long)m*KP + k] = hv;
  }
}

// transpose Eo[b][l][k] -> EoT[b][k][l]
__global__ __launch_bounds__(256) void k_setup_t(const float* __restrict__ Eo, float* __restrict__ EoT){
  __shared__ float tile[64][65];
  int b = blockIdx.y;
  int kt = blockIdx.x / 8, lt = blockIdx.x - kt*8;
  int k0 = kt*64, l0 = lt*64;
  int c = threadIdx.x & 63, rb = threadIdx.x >> 6;
  #pragma unroll
  for (int p = 0; p < 16; ++p){
    int r = p*4 + rb;
    tile[r][c] = (k0 + c < Hd) ? Eo[((long)b*Ll + l0 + r)*Hd + k0 + c] : 0.f;
  }
  __syncthreads();
  #pragma unroll
  for (int p = 0; p < 16; ++p){
    int r = p*4 + rb;
    if (k0 + r < Hd) EoT[((long)b*Hd + k0 + r)*Ll + l0 + c] = tile[c][r];
  }
}

// ---------------- GRU GEMM (split bf16, 3 MFMAs) — R6 loop, XCD-grouped by weight stripe ------
// grid 360: i -> c=i&7, k=i>>3, yt=c+8*(k/15), mt=k%15; yt>=20 exits.
// All 15 mt-blocks of one yt share i%8 -> same XCD -> the 229 KB W-stripe is fetched once/XCD.
__global__ __launch_bounds__(256) void k_ggemm(
    const float* __restrict__ X, const float* __restrict__ Hh,
    const u16* __restrict__ Bhi, const u16* __restrict__ Blo,
    float* __restrict__ Gm)
{
  __shared__ u16 As_hi[32*40], As_lo[32*40];
  __shared__ u16 Bs_hi[128*40], Bs_lo[128*40];
  int tid = threadIdx.x;
  int i = blockIdx.x;
  int cx = i & 7, kk2 = i >> 3;
  int yt = cx + 8*(kk2/15);
  int mt = kk2 % 15;
  if (yt >= 20) return;
  int seg = yt >= 10 ? 1 : 0, nt = seg ? yt-10 : yt;
  const float* A = seg ? Hh : X;
  int m0 = mt*32;
  long brow0 = (long)seg*1280 + (long)nt*128;
  int w = tid>>6, l = tid&63, lr = l&15, kg = l>>4;
  f4 acc[2][2] = {};
  int arow = tid>>3, ac4 = (tid&7)*4;
  int br4 = tid>>2, bc8 = (tid&3)*8;
  for (int ks = 0; ks < 14; ++ks){
    int k0 = ks*32;
    __syncthreads();
    { f4 v = *(const f4*)(A + (long)(m0+arow)*KP + k0 + ac4);
      u16 h0=f2bf(v.x),h1=f2bf(v.y),h2=f2bf(v.z),h3=f2bf(v.w);
      *(ushort4*)&As_hi[arow*40+ac4] = make_ushort4(h0,h1,h2,h3);
      u16 q0=f2bf(v.x-bf2f(h0)),q1=f2bf(v.y-bf2f(h1)),q2=f2bf(v.z-bf2f(h2)),q3=f2bf(v.w-bf2f(h3));
      *(ushort4*)&As_lo[arow*40+ac4] = make_ushort4(q0,q1,q2,q3);
    }
    #pragma unroll
    for (int p = 0; p < 2; ++p){
      long row = brow0 + p*64 + br4;
      *(uint4*)&Bs_hi[(p*64+br4)*40+bc8] = *(const uint4*)(Bhi + row*KP + k0 + bc8);
      *(uint4*)&Bs_lo[(p*64+br4)*40+bc8] = *(const uint4*)(Blo + row*KP + k0 + bc8);
    }
    __syncthreads();
    bf8 ah[2], al[2], bh[2], bl[2];
    #pragma unroll
    for (int ii = 0; ii < 2; ++ii){
      ah[ii] = *(const bf8*)&As_hi[(ii*16+lr)*40 + kg*8];
      al[ii] = *(const bf8*)&As_lo[(ii*16+lr)*40 + kg*8];
    }
    #pragma unroll
    for (int jj = 0; jj < 2; ++jj){
      int r = w*32 + jj*16 + lr;
      bh[jj] = *(const bf8*)&Bs_hi[r*40 + kg*8];
      bl[jj] = *(const bf8*)&Bs_lo[r*40 + kg*8];
    }
    #pragma unroll
    for (int ii = 0; ii < 2; ++ii)
      #pragma unroll
      for (int jj = 0; jj < 2; ++jj){
        acc[ii][jj] = __builtin_amdgcn_mfma_f32_16x16x32_bf16(ah[ii], bh[jj], acc[ii][jj], 0,0,0);
        acc[ii][jj] = __builtin_amdgcn_mfma_f32_16x16x32_bf16(ah[ii], bl[jj], acc[ii][jj], 0,0,0);
        acc[ii][jj] = __builtin_amdgcn_mfma_f32_16x16x32_bf16(al[ii], bh[jj], acc[ii][jj], 0,0,0);
      }
  }
  #pragma unroll
  for (int ii = 0; ii < 2; ++ii)
    #pragma unroll
    for (int jj = 0; jj < 2; ++jj){
      int nl = nt*128 + w*32 + jj*16 + lr;
      if (nl < 1200){
        int col = seg*1200 + nl;
        int mrow = m0 + ii*16 + kg*4;
        #pragma unroll
        for (int r = 0; r < 4; ++r)
          Gm[(long)(mrow+r)*2400 + col] = acc[ii][jj][r];
      }
    }
}

// ---------------- fused GRU-combine + attention + p_gen (+gates), SG=2, shuffle reductions ----
// grid (16, 15): x = b (xcd = b%8 under round-robin -> per-XCD L2 holds 2 b's of Eo/EoT), y = s-group
__global__ __launch_bounds__(512) void k_attn(
    const float* __restrict__ Eo, const float* __restrict__ EoT, const int* __restrict__ cmask,
    const float* __restrict__ Gm, const float* __restrict__ bih, const float* __restrict__ bhh,
    float* __restrict__ Hh, u16* __restrict__ Hbf, const float* __restrict__ X,
    const float* __restrict__ wr, const float* __restrict__ wrb,
    const float* __restrict__ wg, const float* __restrict__ wgb,
    float* __restrict__ cp, float* __restrict__ pgen, float* __restrict__ og, int t)
{
  __shared__ float sh_h[SG][Hd];
  __shared__ float sh_c[SG][Hd];
  __shared__ float sh_p[SG][Ll];
  __shared__ float buf[4*SG*Ll];
  __shared__ float wred[2][SG*8];
  int tid = threadIdx.x, b = blockIdx.x, s0 = blockIdx.y*SG;
  int lane = tid & 63, wid = tid >> 6;

  // GRU combine for our SG rows
  for (int idx = tid; idx < SG*Hd; idx += 512){
    int sg = idx / Hd, j = idx - sg*Hd;
    long m = (long)(s0+sg)*B_ + b;
    const float* g = Gm + m*2400;
    float r = 1.f/(1.f+expf(-(g[j]     + bih[j]     + g[1200+j] + bhh[j])));
    float z = 1.f/(1.f+expf(-(g[400+j] + bih[400+j] + g[1600+j] + bhh[400+j])));
    float n = tanhf(g[800+j] + bih[800+j] + r*(g[2000+j] + bhh[800+j]));
    float h = (1.f-z)*n + z*Hh[m*KP + j];
    sh_h[sg][j] = h;
    Hh[m*KP + j] = h;
    Hbf[m*KP + j] = f2bf(h);
  }
  __syncthreads();

  // scores: thread = (lq=tid&127 -> l0=4*lq, kq=tid>>7), coalesced f4 reads of EoT
  {
    int lq = tid & 127, kq = tid >> 7;
    int l0 = lq*4;
    const float* ebase = EoT + (long)b*Hd*Ll;
    f4 sc[SG];
    #pragma unroll
    for (int sg = 0; sg < SG; ++sg) sc[sg] = f4{0.f,0.f,0.f,0.f};
    int k0 = kq*100;
    for (int k = k0; k < k0+100; k += 4){
      f4 h4[SG];
      #pragma unroll
      for (int sg = 0; sg < SG; ++sg) h4[sg] = *(const f4*)&sh_h[sg][k];
      #pragma unroll
      for (int kk = 0; kk < 4; ++kk){
        f4 e = *(const f4*)&ebase[(long)(k+kk)*Ll + l0];
        #pragma unroll
        for (int sg = 0; sg < SG; ++sg){
          float hk = h4[sg][kk];
          sc[sg].x += e.x*hk; sc[sg].y += e.y*hk; sc[sg].z += e.z*hk; sc[sg].w += e.w*hk;
        }
      }
    }
    #pragma unroll
    for (int sg = 0; sg < SG; ++sg)
      *(f4*)&buf[(kq*SG+sg)*Ll + l0] = sc[sg];
  }
  __syncthreads();

  // combine partials, mask; softmax via wave shuffle + 8-entry cross-wave combine
  float v[SG];
  {
    bool mok = cmask[b*Ll + tid] != 0;
    #pragma unroll
    for (int sg = 0; sg < SG; ++sg){
      float x = buf[sg*Ll+tid] + buf[(SG+sg)*Ll+tid] + buf[(2*SG+sg)*Ll+tid] + buf[(3*SG+sg)*Ll+tid];
      v[sg] = mok ? x : -INF;
    }
  }
  #pragma unroll
  for (int sg = 0; sg < SG; ++sg){
    float m_ = v[sg];
    #pragma unroll
    for (int d = 1; d < 64; d <<= 1) m_ = fmaxf(m_, __shfl_xor(m_, d));
    if (lane == 0) wred[0][sg*8 + wid] = m_;
  }
  __syncthreads();
  float p[SG];
  #pragma unroll
  for (int sg = 0; sg < SG; ++sg){
    float mx = wred[0][sg*8];
    #pragma unroll
    for (int q = 1; q < 8; ++q) mx = fmaxf(mx, wred[0][sg*8+q]);
    p[sg] = expf(v[sg] - mx);
    float s_ = p[sg];
    #pragma unroll
    for (int d = 1; d < 64; d <<= 1) s_ += __shfl_xor(s_, d);
    if (lane == 0) wred[1][sg*8 + wid] = s_;
  }
  __syncthreads();
  #pragma unroll
  for (int sg = 0; sg < SG; ++sg){
    float sum = 0.f;
    #pragma unroll
    for (int q = 0; q < 8; ++q) sum += wred[1][sg*8+q];
    float pp = p[sg] / sum;
    sh_p[sg][tid] = pp;
    cp[((long)(s0+sg)*B_ + b)*Ll + tid] = pp;
  }
  __syncthreads();

  // ctx: thread = (k4 = tid&127 [<100 active], lq = tid>>7)
  {
    int k4 = tid & 127, lq = tid >> 7;
    if (k4 < 100){
      int k = k4*4;
      f4 cacc[SG];
      #pragma unroll
      for (int sg = 0; sg < SG; ++sg) cacc[sg] = f4{0.f,0.f,0.f,0.f};
      for (int li = 0; li < 128; li += 4){
        int l2 = lq*128 + li;
        f4 pv[SG];
        #pragma unroll
        for (int sg = 0; sg < SG; ++sg) pv[sg] = *(const f4*)&sh_p[sg][l2];
        #pragma unroll
        for (int jj = 0; jj < 4; ++jj){
          f4 e = *(const f4*)&Eo[((long)b*Ll + l2 + jj)*Hd + k];
          #pragma unroll
          for (int sg = 0; sg < SG; ++sg){
            float pw = pv[sg][jj];
            cacc[sg].x += e.x*pw; cacc[sg].y += e.y*pw; cacc[sg].z += e.z*pw; cacc[sg].w += e.w*pw;
          }
        }
      }
      #pragma unroll
      for (int sg = 0; sg < SG; ++sg)
        *(f4*)&buf[(lq*SG+sg)*Hd + k] = cacc[sg];
    }
  }
  __syncthreads();
  if (tid < Hd){
    #pragma unroll
    for (int sg = 0; sg < SG; ++sg)
      sh_c[sg][tid] = buf[sg*Hd+tid] + buf[(SG+sg)*Hd+tid] + buf[(2*SG+sg)*Hd+tid] + buf[(3*SG+sg)*Hd+tid];
  }
  __syncthreads();

  // p_gen = sigmoid([h,c,x].wr + b)  (shuffle + 8-entry combine)
  {
    float part[SG];
    #pragma unroll
    for (int sg = 0; sg < SG; ++sg) part[sg] = 0.f;
    for (int j = tid; j < 1200; j += 512){
      float wv = wr[j];
      #pragma unroll
      for (int sg = 0; sg < SG; ++sg){
        float xv;
        if (j < 400) xv = sh_h[sg][j];
        else if (j < 800) xv = sh_c[sg][j-400];
        else xv = X[((long)(s0+sg)*B_ + b)*KP + (j-800)];
        part[sg] += xv*wv;
      }
    }
    #pragma unroll
    for (int sg = 0; sg < SG; ++sg){
      float s_ = part[sg];
      #pragma unroll
      for (int d = 1; d < 64; d <<= 1) s_ += __shfl_xor(s_, d);
      if (lane == 0) wred[0][sg*8 + wid] = s_;
    }
    __syncthreads();
    if (tid < SG){
      float sum = 0.f;
      #pragma unroll
      for (int q = 0; q < 8; ++q) sum += wred[0][tid*8+q];
      pgen[(long)(s0+tid)*B_ + b] = 1.f/(1.f+expf(-(sum + wrb[0])));
    }
  }

  // gates logits at t==0
  if (t == 0){
    for (int g = 0; g < Gg; ++g){
      float pt[SG];
      #pragma unroll
      for (int sg = 0; sg < SG; ++sg) pt[sg] = 0.f;
      if (tid < Hd){
        float wv = wg[g*Hd + tid];
        #pragma unroll
        for (int sg = 0; sg < SG; ++sg) pt[sg] = sh_c[sg][tid]*wv;
      }
      __syncthreads();   // protect wred[1] reuse across g iterations
      #pragma unroll
      for (int sg = 0; sg < SG; ++sg){
        float s_ = pt[sg];
        #pragma unroll
        for (int d = 1; d < 64; d <<= 1) s_ += __shfl_xor(s_, d);
        if (lane == 0) wred[1][sg*8 + wid] = s_;
      }
      __syncthreads();
      if (tid < SG){
        float sum = 0.f;
        #pragma unroll
        for (int q = 0; q < 8; ++q) sum += wred[1][tid*8+q];
        og[((long)b*S_ + (s0+tid))*Gg + g] = sum + wgb[g];
      }
    }
  }
}

// ---------------- vocab GEMM — R6 structure; 1D grid remapped so the 4 mt-blocks of each
// B-stripe share an XCD (i%8 == ns%8 under round-robin) ----------
// grid 576: i -> c=i&7, j=i>>3, ns=c+8*(j>>2), mt=j&3; ns>=141 exits
__global__ __launch_bounds__(256) void k_vgemm(
    const u16* __restrict__ Abf, const u16* __restrict__ Bhi,
    u16* __restrict__ E, float* __restrict__ pmax, float* __restrict__ psum)
{
  __shared__ u16 As[128*40], Bs[128*40];
  __shared__ float redm[2][128], reds[2][128];
  int tid = threadIdx.x;
  int i = blockIdx.x;
  int cx = i & 7, j = i >> 3;
  int ns = cx + 8*(j >> 2);
  int mt = j & 3;
  if (ns >= NST) return;
  int m0 = (mt == 3) ? 352 : mt*128;   // rows 352-383 duplicated by mt=2: bitwise-identical writes
  long brow0 = (long)ns*128;
  int w = tid>>6, l = tid&63, lr = l&15, kg = l>>4;
  int wm = w>>1, wn = w&1;
  int srow = tid>>1, sc8 = (tid&1)*16;
  const u16* aP = Abf + (long)(m0+srow)*KP + sc8;
  const u16* bP = Bhi + (brow0+srow)*KP + sc8;
  int so = srow*40 + sc8;
  f4 acc[4][4] = {};
  for (int ks = 0; ks < 14; ++ks){
    int k0 = ks*32;
    __syncthreads();
    *(uint4*)&As[so]     = *(const uint4*)(aP + k0);
    *(uint4*)&As[so + 8] = *(const uint4*)(aP + k0 + 8);
    *(uint4*)&Bs[so]     = *(const uint4*)(bP + k0);
    *(uint4*)&Bs[so + 8] = *(const uint4*)(bP + k0 + 8);
    __syncthreads();
    bf8 a[4], b[4];
    #pragma unroll
    for (int ii = 0; ii < 4; ++ii) a[ii] = *(const bf8*)&As[(wm*64 + ii*16 + lr)*40 + kg*8];
    #pragma unroll
    for (int jj = 0; jj < 4; ++jj) b[jj] = *(const bf8*)&Bs[(wn*64 + jj*16 + lr)*40 + kg*8];
    #pragma unroll
    for (int ii = 0; ii < 4; ++ii)
      #pragma unroll
      for (int jj = 0; jj < 4; ++jj)
        acc[ii][jj] = __builtin_amdgcn_mfma_f32_16x16x32_bf16(a[ii], b[jj], acc[ii][jj], 0,0,0);
  }
  // epilogue: per-row stripe max
  #pragma unroll
  for (int ii = 0; ii < 4; ++ii)
    #pragma unroll
    for (int r = 0; r < 4; ++r){
      float mxv = -INF;
      #pragma unroll
      for (int jj = 0; jj < 4; ++jj){
        int col = (int)brow0 + wn*64 + jj*16 + lr;
        if (col < Vv) mxv = fmaxf(mxv, acc[ii][jj][r]);
      }
      #pragma unroll
      for (int d = 1; d < 16; d <<= 1) mxv = fmaxf(mxv, __shfl_xor(mxv, d));
      if (lr == 0) redm[wn][wm*64 + ii*16 + kg*4 + r] = mxv;
    }
  __syncthreads();
  // exp, store bf16 E, per-row sums
  #pragma unroll
  for (int ii = 0; ii < 4; ++ii)
    #pragma unroll
    for (int r = 0; r < 4; ++r){
      int rl = wm*64 + ii*16 + kg*4 + r;
      float cmx = fmaxf(redm[0][rl], redm[1][rl]);
      float ssum = 0.f;
      long erow = (long)(m0 + rl)*EW;
      #pragma unroll
      for (int jj = 0; jj < 4; ++jj){
        int col = (int)brow0 + wn*64 + jj*16 + lr;
        float e = (col < Vv) ? expf(acc[ii][jj][r] - cmx) : 0.f;
        E[erow + col] = f2bf(e);
        ssum += e;
      }
      #pragma unroll
      for (int d = 1; d < 16; d <<= 1) ssum += __shfl_xor(ssum, d);
      if (lr == 0) reds[wn][rl] = ssum;
    }
  __syncthreads();
  if (tid < 128){
    pmax[(long)(m0+tid)*NST + ns] = fmaxf(redm[0][tid], redm[1][tid]);
    psum[(long)(m0+tid)*NST + ns] = reds[0][tid] + reds[1][tid];
  }
}

// ---------------- fused: LSE-combine + finalize + scatter + argmax + greedy feedback ----------
__global__ __launch_bounds__(512) void k_final(
    const u16* __restrict__ E, const float* __restrict__ pmax, const float* __restrict__ psum,
    const float* __restrict__ pgen, const float* __restrict__ cp,
    const int* __restrict__ cidx, const int* __restrict__ cmask,
    const float* __restrict__ emb, float* __restrict__ out, float* __restrict__ X, int t)
{
  __shared__ float scat[Vv];
  __shared__ float scale[NST];
  __shared__ float am[256], asum[256];
  __shared__ float rv[512];
  __shared__ int   ri[512];
  int tid = threadIdx.x, m = blockIdx.x;
  int b = m & 15, s = m >> 4;
  if (tid < 256){
    am[tid]   = tid < NST ? pmax[(long)m*NST + tid] : -1e30f;
    asum[tid] = tid < NST ? psum[(long)m*NST + tid] : 0.f;
  }
  for (int i = tid; i < Vv; i += 512) scat[i] = 0.f;
  __syncthreads();
  for (int o = 128; o > 0; o >>= 1){
    if (tid < o){
      float m2 = am[tid+o], M = fmaxf(am[tid], m2);
      asum[tid] = asum[tid]*expf(am[tid]-M) + asum[tid+o]*expf(m2-M);
      am[tid] = M;
    }
    __syncthreads();
  }
  float gmx = am[0], pg = pgen[m];
  float sc0 = pg / asum[0];
  if (tid < NST) scale[tid] = sc0 * expf(pmax[(long)m*NST + tid] - gmx);
  if (cmask[b*Ll + tid]){
    float vv = (1.f - pg)*cp[(long)m*Ll + tid];
    atomicAdd(&scat[cidx[b*Ll + tid]], vv);
  }
  __syncthreads();
  long eb = (long)m*EW;
  long ob = ((long)(b*S_ + s)*Tt + t)*(long)Vv;
  float bv = -1.f; int bi = 0;
  for (int i = tid; i < Vv/8; i += 512){
    u16x8 ev = *(const u16x8*)&E[eb + i*8];
    float sc = scale[(i*8) >> 7];
    f4 s0 = *(const f4*)&scat[i*8];
    f4 s1 = *(const f4*)&scat[i*8 + 4];
    f4 o0, o1;
    o0.x = sc*bf2f(ev[0]) + s0.x; o0.y = sc*bf2f(ev[1]) + s0.y;
    o0.z = sc*bf2f(ev[2]) + s0.z; o0.w = sc*bf2f(ev[3]) + s0.w;
    o1.x = sc*bf2f(ev[4]) + s1.x; o1.y = sc*bf2f(ev[5]) + s1.y;
    o1.z = sc*bf2f(ev[6]) + s1.z; o1.w = sc*bf2f(ev[7]) + s1.w;
    *(f4*)&out[ob + i*8]     = o0;
    *(f4*)&out[ob + i*8 + 4] = o1;
    int n0 = i*8;
    if (o0.x > bv){ bv = o0.x; bi = n0;   }
    if (o0.y > bv){ bv = o0.y; bi = n0+1; }
    if (o0.z > bv){ bv = o0.z; bi = n0+2; }
    if (o0.w > bv){ bv = o0.w; bi = n0+3; }
    if (o1.x > bv){ bv = o1.x; bi = n0+4; }
    if (o1.y > bv){ bv = o1.y; bi = n0+5; }
    if (o1.z > bv){ bv = o1.z; bi = n0+6; }
    if (o1.w > bv){ bv = o1.w; bi = n0+7; }
  }
  rv[tid] = bv; ri[tid] = bi;
  __syncthreads();
  for (int o = 256; o > 0; o >>= 1){
    if (tid < o){
      float v2 = rv[tid+o]; int i2 = ri[tid+o];
      if (v2 > rv[tid] || (v2 == rv[tid] && i2 < ri[tid])){ rv[tid] = v2; ri[tid] = i2; }
    }
    __syncthreads();
  }
  int win = ri[0];
  if (tid < Hd) X[(long)m*KP + tid] = emb[(long)win*Hd + tid];
}

// ---------------- launcher ----------------
extern "C" void kernel_launch(void* const* d_in, const int* in_sizes, int n_in,
                              void* d_out, int out_size, void* d_ws, size_t ws_size,
                              hipStream_t stream)
{
  const float* ehid  = (const float*)d_in[0];
  const float* eout  = (const float*)d_in[1];
  const int*   cidx  = (const int*)d_in[2];
  const int*   cmask = (const int*)d_in[3];
  const float* emb   = (const float*)d_in[5];
  const float* semb  = (const float*)d_in[6];
  const int*   didx  = (const int*)d_in[7];
  const int*   sidx  = (const int*)d_in[8];
  const float* Wih   = (const float*)d_in[9];
  const float* Whh   = (const float*)d_in[10];
  const float* bih   = (const float*)d_in[11];
  const float* bhh   = (const float*)d_in[12];
  const float* wr    = (const float*)d_in[13];
  const float* wrb   = (const float*)d_in[14];
  const float* wg    = (const float*)d_in[15];
  const float* wgb   = (const float*)d_in[16];
  float* out = (float*)d_out;

  char* ws = (char*)d_ws;
  u16*   ws_hi = (u16*)(ws + 0);            //  2,293,760
  u16*   ws_lo = (u16*)(ws + 2293760);      //  2,293,760
  u16*   ebf   = (u16*)(ws + 4587520);      // 16,285,696
  float* EoT   = (float*)(ws + 20873216);   // 13,107,200
  float* X     = (float*)(ws + 33980416);   //    860,160
  float* Hh    = (float*)(ws + 34840576);   //    860,160
  u16*   Hbf   = (u16*)(ws + 35700736);     //    458,752 (512 rows)
  float* Gm    = (float*)(ws + 36159488);   //  4,608,000
  u16*   E     = (u16*)(ws + 40767488);     // 18,481,152 (512 x 18048 bf16)
  float* cp    = (float*)(ws + 59248640);   //    983,040
  float* pg    = (float*)(ws + 60231680);   //      2,048
  float* pmax  = (float*)(ws + 60233728);   //    288,768
  float* psum  = (float*)(ws + 60522496);   //    288,768
  float* og = out + (long)B_*S_*Tt*Vv;

  k_setup_w <<<4480, 256, 0, stream>>>(Wih, Whh, ws_hi, ws_lo);
  k_setup_e <<<4096, 256, 0, stream>>>(emb, ebf);
  k_setup_xh<<<512, 448, 0, stream>>>(ehid, semb, didx, sidx, X, Hh, Hbf);
  k_setup_t <<<dim3(56,16), 256, 0, stream>>>(eout, EoT);

  for (int t = 0; t < Tt; ++t){
    k_ggemm <<<360, 256, 0, stream>>>(X, Hh, ws_hi, ws_lo, Gm);
    k_attn  <<<dim3(16,15), 512, 0, stream>>>(eout, EoT, cmask, Gm, bih, bhh, Hh, Hbf, X,
                                              wr, wrb, wg, wgb, cp, pg, og, t);
    k_vgemm <<<576, 256, 0, stream>>>(Hbf, ebf, E, pmax, psum);
    k_final <<<480, 512, 0, stream>>>(E, pmax, psum, pg, cp, cidx, cmask, emb, out, X, t);
  }
}